// Round 3
// baseline (398.255 us; speedup 1.0000x reference)
//
#include <hip/hip_runtime.h>
#include <math.h>

#define B 8
#define N 1024
#define L 16
#define D 256
#define H 4
#define DH 64
#define NLAYERS 2

typedef __attribute__((ext_vector_type(8))) short short8;
typedef __attribute__((ext_vector_type(4))) float f32x4;

__device__ inline unsigned short f2bf(float x) {
    unsigned u = __float_as_uint(x);
    u = (u + 0x7fff + ((u >> 16) & 1)) >> 16;  // RNE
    return (unsigned short)u;
}

// -------- workspace layout (float units) --------
// h      : B*N*D                 = 2097152
// hp     : B*H*N*DH              = 2097152
// srcv/dstv/rowmax/rowsum        = 4 x 32768
// h_bf   : B*N*D ushort          = 1048576 floats
// WhT    : B*H*DH*N ushort       = 1048576 floats
// WT_bf  : H*DH*D ushort         = 32768 floats
// wa_src : H*D                   = 1024
// wa_dst : H*D                   = 1024
// pack   : B*N*16 uint64 (1 MB)  = 262144 floats

// ---- one-time: pack adj (+self-loop) into bitmasks: pack[bn][it] bit m ----
__global__ __launch_bounds__(256) void k_packadj(const int* __restrict__ adj,
                                                 unsigned long long* __restrict__ pack) {
    int row = blockIdx.x * 4 + (threadIdx.x >> 6);  // bn in [0, B*N)
    int lane = threadIdx.x & 63;
    int n = row & (N - 1);
    const int* arow = adj + (long)row * N;
    unsigned long long* prow = pack + (size_t)row * 16;
#pragma unroll
    for (int it = 0; it < 16; ++it) {
        int m = lane + it * 64;
        unsigned long long bits = __ballot(arow[m] != 0 || m == n);
        if (lane == 0) prow[it] = bits;
    }
}

// node_feat: mean over token embeddings -> h fp32 + h_bf bf16
__global__ __launch_bounds__(256) void k_nodefeat(const int* __restrict__ nodes,
                                                  const float* __restrict__ emb,
                                                  float* __restrict__ h,
                                                  unsigned short* __restrict__ h_bf) {
    int bn = blockIdx.x * 4 + (threadIdx.x >> 6);
    int d4 = (threadIdx.x & 63) * 4;
    const int* np = nodes + bn * L;
    float4 s = make_float4(0.f, 0.f, 0.f, 0.f);
#pragma unroll
    for (int l = 0; l < L; ++l) {
        float4 v = *(const float4*)&emb[(size_t)np[l] * D + d4];
        s.x += v.x; s.y += v.y; s.z += v.z; s.w += v.w;
    }
    s.x *= (1.0f / L); s.y *= (1.0f / L); s.z *= (1.0f / L); s.w *= (1.0f / L);
    *(float4*)&h[(size_t)bn * D + d4] = s;
    ushort4 bv;
    bv.x = f2bf(s.x); bv.y = f2bf(s.y); bv.z = f2bf(s.z); bv.w = f2bf(s.w);
    *(ushort4*)&h_bf[(size_t)bn * D + d4] = bv;
}

// per-layer prep: WT_bf[h][dh][d] = bf16(W[l,h,d,dh]); wa_{src,dst}[h][d] = W[l,h,d,:]·a
__global__ __launch_bounds__(256) void k_wprep(const float* __restrict__ W,
                                               const float* __restrict__ a_src,
                                               const float* __restrict__ a_dst,
                                               unsigned short* __restrict__ WT_bf,
                                               float* __restrict__ wa_src,
                                               float* __restrict__ wa_dst, int layer) {
    int hh = blockIdx.x;
    int t = threadIdx.x;
    const float* Wl = W + ((size_t)(layer * H + hh) * D) * DH;  // [d][k]
    // transpose+convert: thread (dh = t&63, q = t>>6) covers d in [q*64, q*64+64)
    int dh = t & 63, q = t >> 6;
    for (int d = q * 64; d < q * 64 + 64; ++d) {
        WT_bf[((size_t)(hh * DH + dh)) * D + d] = f2bf(Wl[(size_t)d * DH + dh]);
    }
    // wa: thread t = d
    const float* as = a_src + (layer * H + hh) * DH;
    const float* ad = a_dst + (layer * H + hh) * DH;
    float s = 0.f, dd = 0.f;
#pragma unroll 8
    for (int k = 0; k < DH; ++k) {
        float w = Wl[(size_t)t * DH + k];
        s += w * as[k];
        dd += w * ad[k];
    }
    wa_src[hh * D + t] = s;
    wa_dst[hh * D + t] = dd;
}

// src[bh,n] = h[b,n,:]·wa_src[h,:]  (== Wh·a_src exactly in real arithmetic)
__global__ __launch_bounds__(256) void k_srcdst(const float* __restrict__ h,
                                                const float* __restrict__ wa_src,
                                                const float* __restrict__ wa_dst,
                                                float* __restrict__ srcv,
                                                float* __restrict__ dstv) {
    __shared__ float red[8][4];
    int bn = blockIdx.x;
    int b = bn >> 10, n = bn & 1023;
    int c = threadIdx.x;
    float x = h[(size_t)bn * D + c];
    float sv[4], dv[4];
#pragma unroll
    for (int hh = 0; hh < H; ++hh) {
        sv[hh] = x * wa_src[hh * D + c];
        dv[hh] = x * wa_dst[hh * D + c];
    }
#pragma unroll
    for (int off = 32; off; off >>= 1) {
#pragma unroll
        for (int hh = 0; hh < H; ++hh) {
            sv[hh] += __shfl_xor(sv[hh], off, 64);
            dv[hh] += __shfl_xor(dv[hh], off, 64);
        }
    }
    int w = c >> 6, lane = c & 63;
    if (lane < 4) red[lane][w] = sv[lane];
    else if (lane < 8) red[4 + lane - 4][w] = dv[lane - 4];
    __syncthreads();
    if (c < 8) {
        float v = red[c][0] + red[c][1] + red[c][2] + red[c][3];
        int hh = c & 3;
        if (c < 4) srcv[(b * H + hh) * N + n] = v;
        else dstv[(b * H + hh) * N + n] = v;
    }
}

// Wh^T bf16 via MFMA: WhT[bh][dh][n] = (h @ W[l,h])^T
__global__ __launch_bounds__(256) void k_wh(const unsigned short* __restrict__ h_bf,
                                            const unsigned short* __restrict__ WT_bf,
                                            unsigned short* __restrict__ WhT) {
    int bt = blockIdx.x;   // b*16 + nt
    int hh = blockIdx.y;
    int b = bt >> 4;
    int n0 = (bt & 15) * 64;
    int tid = threadIdx.x;
    int w = tid >> 6, lane = tid & 63;
    int rowLane = lane & 15, quad = lane >> 4;
    int n = n0 + w * 16 + rowLane;
    int bh = b * H + hh;
    const unsigned short* hrow = h_bf + ((size_t)(b * N + n)) * D;
    f32x4 acc[4] = {};
#pragma unroll
    for (int ki = 0; ki < D / 32; ++ki) {
        short8 af = *(const short8*)(hrow + ki * 32 + quad * 8);
#pragma unroll
        for (int c = 0; c < 4; ++c) {
            short8 bf = *(const short8*)&WT_bf[((size_t)(hh * DH + c * 16 + rowLane)) * D + ki * 32 + quad * 8];
            acc[c] = __builtin_amdgcn_mfma_f32_16x16x32_bf16(af, bf, acc[c], 0, 0, 0);
        }
    }
    // C/D: col=lane&15, row=quad*4+r  -> write transposed (col-major WhT)
#pragma unroll
    for (int c = 0; c < 4; ++c) {
        ushort4 v;
        v.x = f2bf(acc[c][0]); v.y = f2bf(acc[c][1]);
        v.z = f2bf(acc[c][2]); v.w = f2bf(acc[c][3]);
        *(ushort4*)&WhT[((size_t)(bh * DH + c * 16 + rowLane)) * N + n0 + w * 16 + quad * 4] = v;
    }
}

// Per-row softmax stats over masked e[n,m] = lrelu(src[n]+dst[m]).
__global__ __launch_bounds__(256) void k_rowstats(const unsigned long long* __restrict__ pack,
                                                  const float* __restrict__ srcv,
                                                  const float* __restrict__ dstv,
                                                  float* __restrict__ rowmax,
                                                  float* __restrict__ rowsum) {
    int bn = blockIdx.x;
    int b = bn >> 10, n = bn & 1023;
    int hh = threadIdx.x >> 6, lane = threadIdx.x & 63;
    int bh = b * H + hh;
    const unsigned long long* prow = pack + (size_t)bn * 16;
    const float* dstp = dstv + bh * N;
    float src = srcv[bh * N + n];
    float mx = -1e30f, sum = 0.f;
#pragma unroll
    for (int it = 0; it < N / 64; ++it) {
        int m = lane + it * 64;
        bool mask = (prow[it] >> lane) & 1;
        float e = src + dstp[m];
        e = e > 0.f ? e : 0.2f * e;
        float nm = mask ? fmaxf(mx, e) : mx;
        sum = sum * __expf(mx - nm) + (mask ? __expf(e - nm) : 0.f);
        mx = nm;
    }
#pragma unroll
    for (int off = 32; off; off >>= 1) {
        float mo = __shfl_xor(mx, off, 64);
        float so = __shfl_xor(sum, off, 64);
        float M = fmaxf(mx, mo);
        sum = sum * __expf(mx - M) + so * __expf(mo - M);
        mx = M;
    }
    if (lane == 0) {
        rowmax[bh * N + n] = mx;
        rowsum[bh * N + n] = sum;
    }
}

// h_prime = alpha @ Wh via bf16 MFMA; alpha generated in A-frag layout from
// bit-packed adjacency. Block = (bh, 64-row tile); wave w -> rows n0+16w..+15.
__global__ __launch_bounds__(256) void k_attn(const unsigned long long* __restrict__ pack,
                                              const float* __restrict__ srcv,
                                              const float* __restrict__ dstv,
                                              const float* __restrict__ rowmax,
                                              const float* __restrict__ rowsum,
                                              const unsigned short* __restrict__ WhT,
                                              float* __restrict__ hp) {
    int tid = threadIdx.x;
    int bt = blockIdx.x;
    int bh = bt >> 4;
    int n0 = (bt & 15) * 64;
    int b = bh >> 2;
    int w = tid >> 6, lane = tid & 63;
    int rowLane = lane & 15, quad = lane >> 4;
    int n = n0 + w * 16 + rowLane;
    const unsigned char* pb = (const unsigned char*)(pack + ((size_t)(b * N + n)) * 16);
    const float* dq = dstv + bh * N + quad * 8;
    float src = srcv[bh * N + n];
    float mx = rowmax[bh * N + n];
    float inv = 1.0f / rowsum[bh * N + n];
    const unsigned short* wp0 = WhT + ((size_t)(bh * DH + 0 * 16 + rowLane)) * N + quad * 8;
    const unsigned short* wp1 = wp0 + (size_t)16 * N;
    const unsigned short* wp2 = wp0 + (size_t)32 * N;
    const unsigned short* wp3 = wp0 + (size_t)48 * N;

    f32x4 acc[4] = {};
#pragma unroll 2
    for (int mt = 0; mt < 16; ++mt) {
#pragma unroll
        for (int kk = 0; kk < 2; ++kk) {
            int mo = mt * 64 + kk * 32;
            unsigned bits = pb[mt * 8 + kk * 4 + quad];
            float4 d0 = *(const float4*)(dq + mo);
            float4 d1 = *(const float4*)(dq + mo + 4);
            float dd[8] = {d0.x, d0.y, d0.z, d0.w, d1.x, d1.y, d1.z, d1.w};
            short8 af;
#pragma unroll
            for (int j = 0; j < 8; ++j) {
                float e = src + dd[j];
                e = e > 0.f ? e : 0.2f * e;
                float p = ((bits >> j) & 1) ? __expf(e - mx) * inv : 0.f;
                af[j] = (short)f2bf(p);
            }
            acc[0] = __builtin_amdgcn_mfma_f32_16x16x32_bf16(af, *(const short8*)(wp0 + mo), acc[0], 0, 0, 0);
            acc[1] = __builtin_amdgcn_mfma_f32_16x16x32_bf16(af, *(const short8*)(wp1 + mo), acc[1], 0, 0, 0);
            acc[2] = __builtin_amdgcn_mfma_f32_16x16x32_bf16(af, *(const short8*)(wp2 + mo), acc[2], 0, 0, 0);
            acc[3] = __builtin_amdgcn_mfma_f32_16x16x32_bf16(af, *(const short8*)(wp3 + mo), acc[3], 0, 0, 0);
        }
    }
#pragma unroll
    for (int c = 0; c < 4; ++c) {
#pragma unroll
        for (int r = 0; r < 4; ++r) {
            int nout = n0 + w * 16 + quad * 4 + r;
            hp[((size_t)bh * N + nout) * DH + c * 16 + rowLane] = acc[c][r];
        }
    }
}

// out = LN(h + concat(hp)); also emit bf16 copy for next layer's MFMA A.
__global__ __launch_bounds__(256) void k_ln(const float* __restrict__ h,
                                            const float* __restrict__ hp,
                                            const float* __restrict__ scale,
                                            const float* __restrict__ bias,
                                            float* __restrict__ out,
                                            unsigned short* __restrict__ out_bf,
                                            int layer, int write_bf) {
    __shared__ float red[8];
    int bn = blockIdx.x;
    int b = bn >> 10, n = bn & 1023;
    int c = threadIdx.x;
    int hh = c >> 6, k = c & 63;
    float x = h[(size_t)bn * D + c] + hp[((size_t)(b * H + hh) * N + n) * DH + k];
    float s = x, s2 = x * x;
#pragma unroll
    for (int off = 32; off; off >>= 1) {
        s += __shfl_xor(s, off, 64);
        s2 += __shfl_xor(s2, off, 64);
    }
    int w = c >> 6, lane = c & 63;
    if (lane == 0) { red[w] = s; red[4 + w] = s2; }
    __syncthreads();
    s = red[0] + red[1] + red[2] + red[3];
    s2 = red[4] + red[5] + red[6] + red[7];
    float mu = s * (1.0f / D);
    float var = s2 * (1.0f / D) - mu * mu;
    float r = rsqrtf(var + 1e-5f);
    float y = (x - mu) * r * scale[layer * D + c] + bias[layer * D + c];
    out[(size_t)bn * D + c] = y;
    if (write_bf) out_bf[(size_t)bn * D + c] = f2bf(y);
}

__global__ void k_len(const int* __restrict__ len, float* __restrict__ out) {
    int i = threadIdx.x;
    if (i < B) out[i] = (float)len[i];
}

extern "C" void kernel_launch(void* const* d_in, const int* in_sizes, int n_in,
                              void* d_out, int out_size, void* d_ws, size_t ws_size,
                              hipStream_t stream) {
    const int* cfg_adj = (const int*)d_in[0];
    const int* cfg_nodes = (const int*)d_in[1];
    const int* cfg_len = (const int*)d_in[2];
    const float* emb = (const float*)d_in[3];
    const float* W = (const float*)d_in[4];
    const float* a_src = (const float*)d_in[5];
    const float* a_dst = (const float*)d_in[6];
    const float* ln_scale = (const float*)d_in[7];
    const float* ln_bias = (const float*)d_in[8];
    float* out = (float*)d_out;
    float* ws = (float*)d_ws;

    float* h = ws;
    float* hp = h + (size_t)B * N * D;
    float* srcv = hp + (size_t)B * H * N * DH;
    float* dstv = srcv + (size_t)B * H * N;
    float* rowmax = dstv + (size_t)B * H * N;
    float* rowsum = rowmax + (size_t)B * H * N;
    unsigned short* h_bf = (unsigned short*)(rowsum + (size_t)B * H * N);
    unsigned short* WhT = h_bf + (size_t)B * N * D;
    unsigned short* WT_bf = WhT + (size_t)B * H * DH * N;
    float* wa_src = (float*)(WT_bf + (size_t)H * DH * D);
    float* wa_dst = wa_src + H * D;
    unsigned long long* pack = (unsigned long long*)(wa_dst + H * D);

    k_packadj<<<B * N / 4, 256, 0, stream>>>(cfg_adj, pack);
    k_nodefeat<<<B * N / 4, 256, 0, stream>>>(cfg_nodes, emb, h, h_bf);
    for (int l = 0; l < NLAYERS; ++l) {
        k_wprep<<<H, 256, 0, stream>>>(W, a_src, a_dst, WT_bf, wa_src, wa_dst, l);
        k_srcdst<<<B * N, 256, 0, stream>>>(h, wa_src, wa_dst, srcv, dstv);
        k_wh<<<dim3(B * 16, H), 256, 0, stream>>>(h_bf, WT_bf, WhT);
        k_rowstats<<<B * N, 256, 0, stream>>>(pack, srcv, dstv, rowmax, rowsum);
        k_attn<<<B * H * 16, 256, 0, stream>>>(pack, srcv, dstv, rowmax, rowsum, WhT, hp);
        k_ln<<<B * N, 256, 0, stream>>>(h, hp, ln_scale, ln_bias,
                                        (l == NLAYERS - 1) ? out : h, h_bf,
                                        l, l < NLAYERS - 1 ? 1 : 0);
    }
    k_len<<<1, 64, 0, stream>>>(cfg_len, out + (size_t)B * N * D);
}

// Round 4
// 331.093 us; speedup vs baseline: 1.2028x; 1.2028x over previous
//
#include <hip/hip_runtime.h>
#include <math.h>

#define B 8
#define N 1024
#define L 16
#define D 256
#define H 4
#define DH 64
#define NLAYERS 2

typedef __attribute__((ext_vector_type(8))) short short8;
typedef __attribute__((ext_vector_type(4))) float f32x4;

__device__ inline unsigned short f2bf(float x) {
    unsigned u = __float_as_uint(x);
    u = (u + 0x7fff + ((u >> 16) & 1)) >> 16;  // RNE
    return (unsigned short)u;
}

// -------- workspace layout (float units) --------
// h      : B*N*D f32             = 2097152
// hp     : B*H*N*DH f32          = 2097152
// srcv/dstv/rowmax/rowsum        = 4 x 32768
// h_bf   : B*N*D ushort          = 1048576 floats
// WhT    : B*H*DH*N ushort       = 1048576 floats
// WT_bf  : NLAYERS*H*DH*D ushort = 131072 ushort
// wa_src/wa_dst : NLAYERS*H*D    = 2048 each
// pack   : B*N*16 uint64         = 262144 floats

// ---- one-time: pack adj (+self-loop) into bitmasks ----
__global__ __launch_bounds__(256) void k_packadj(const int* __restrict__ adj,
                                                 unsigned long long* __restrict__ pack) {
    int row = blockIdx.x * 4 + (threadIdx.x >> 6);  // bn in [0, B*N)
    int lane = threadIdx.x & 63;
    int n = row & (N - 1);
    const int* arow = adj + (long)row * N;
    unsigned long long* prow = pack + (size_t)row * 16;
#pragma unroll
    for (int it = 0; it < 16; ++it) {
        int m = lane + it * 64;
        unsigned long long bits = __ballot(arow[m] != 0 || m == n);
        if (lane == 0) prow[it] = bits;
    }
}

// one-time: WT_bf[lh][dh][d] = bf16(W[lh,d,dh]);  wa_*[lh][d] = W[lh,d,:]·a_*
__global__ __launch_bounds__(256) void k_wprep(const float* __restrict__ W,
                                               const float* __restrict__ a_src,
                                               const float* __restrict__ a_dst,
                                               unsigned short* __restrict__ WT_bf,
                                               float* __restrict__ wa_src,
                                               float* __restrict__ wa_dst) {
    int lh = blockIdx.x;   // l*H+h
    int q = blockIdx.y;    // d-quarter
    int t = threadIdx.x;
    const float* Wl = W + (size_t)lh * D * DH;
    int dh = t & 63;
    int d0 = q * 64 + (t >> 6) * 16;
#pragma unroll
    for (int i = 0; i < 16; ++i) {
        int d = d0 + i;
        WT_bf[((size_t)lh * DH + dh) * D + d] = f2bf(Wl[(size_t)d * DH + dh]);
    }
    if (q == 0) {
        const float* as = a_src + lh * DH;
        const float* ad = a_dst + lh * DH;
        float s = 0.f, dd = 0.f;
#pragma unroll 8
        for (int k = 0; k < DH; ++k) {
            float w = Wl[(size_t)t * DH + k];
            s += w * as[k];
            dd += w * ad[k];
        }
        wa_src[lh * D + t] = s;
        wa_dst[lh * D + t] = dd;
    }
}

// node_feat + fused layer-0 src/dst projections
__global__ __launch_bounds__(256) void k_nodefeat(const int* __restrict__ nodes,
                                                  const float* __restrict__ emb,
                                                  const float* __restrict__ wa_src,
                                                  const float* __restrict__ wa_dst,
                                                  float* __restrict__ h,
                                                  unsigned short* __restrict__ h_bf,
                                                  float* __restrict__ srcv,
                                                  float* __restrict__ dstv) {
    int bn = blockIdx.x * 4 + (threadIdx.x >> 6);
    int lane = threadIdx.x & 63;
    int d4 = lane * 4;
    const int* np = nodes + bn * L;
    float4 s = make_float4(0.f, 0.f, 0.f, 0.f);
#pragma unroll
    for (int l = 0; l < L; ++l) {
        float4 v = *(const float4*)&emb[(size_t)np[l] * D + d4];
        s.x += v.x; s.y += v.y; s.z += v.z; s.w += v.w;
    }
    s.x *= (1.0f / L); s.y *= (1.0f / L); s.z *= (1.0f / L); s.w *= (1.0f / L);
    *(float4*)&h[(size_t)bn * D + d4] = s;
    ushort4 bv;
    bv.x = f2bf(s.x); bv.y = f2bf(s.y); bv.z = f2bf(s.z); bv.w = f2bf(s.w);
    *(ushort4*)&h_bf[(size_t)bn * D + d4] = bv;
    // fused src/dst for layer 0
    float sv[4], dv[4];
#pragma unroll
    for (int hh = 0; hh < H; ++hh) {
        float4 ws = *(const float4*)&wa_src[hh * D + d4];
        float4 wd = *(const float4*)&wa_dst[hh * D + d4];
        sv[hh] = s.x * ws.x + s.y * ws.y + s.z * ws.z + s.w * ws.w;
        dv[hh] = s.x * wd.x + s.y * wd.y + s.z * wd.z + s.w * wd.w;
    }
#pragma unroll
    for (int off = 32; off; off >>= 1) {
#pragma unroll
        for (int hh = 0; hh < H; ++hh) {
            sv[hh] += __shfl_xor(sv[hh], off, 64);
            dv[hh] += __shfl_xor(dv[hh], off, 64);
        }
    }
    if (lane == 0) {
        int b = bn >> 10, n = bn & 1023;
#pragma unroll
        for (int hh = 0; hh < H; ++hh) {
            srcv[(b * H + hh) * N + n] = sv[hh];
            dstv[(b * H + hh) * N + n] = dv[hh];
        }
    }
}

// Wh^T bf16 via MFMA, split-K across waves. Block = (b, 16-row tile, head).
__global__ __launch_bounds__(256) void k_wh(const unsigned short* __restrict__ h_bf,
                                            const unsigned short* __restrict__ WT_l,
                                            unsigned short* __restrict__ WhT) {
    __shared__ float red[4][16][64];
    int bt = blockIdx.x;       // b*64 + nt
    int hh = blockIdx.y;
    int b = bt >> 6;
    int n0 = (bt & 63) * 16;
    int tid = threadIdx.x;
    int w = tid >> 6, lane = tid & 63;
    int rowLane = lane & 15, quad = lane >> 4;
    int n = n0 + rowLane;
    int bh = b * H + hh;
    const unsigned short* hrow = h_bf + ((size_t)(b * N + n)) * D + w * 64;
    f32x4 acc[4] = {};
#pragma unroll
    for (int kk = 0; kk < 2; ++kk) {
        short8 af = *(const short8*)(hrow + kk * 32 + quad * 8);
#pragma unroll
        for (int c = 0; c < 4; ++c) {
            short8 bf = *(const short8*)&WT_l[((size_t)(hh * DH + c * 16 + rowLane)) * D + w * 64 + kk * 32 + quad * 8];
            acc[c] = __builtin_amdgcn_mfma_f32_16x16x32_bf16(af, bf, acc[c], 0, 0, 0);
        }
    }
#pragma unroll
    for (int c = 0; c < 4; ++c)
#pragma unroll
        for (int r = 0; r < 4; ++r)
            red[w][quad * 4 + r][c * 16 + rowLane] = acc[c][r];
    __syncthreads();
    // thread: dh = tid&63, 4 consecutive n
    int dh = tid & 63, n4 = (tid >> 6) * 4;
    ushort4 o;
    float v0 = red[0][n4 + 0][dh] + red[1][n4 + 0][dh] + red[2][n4 + 0][dh] + red[3][n4 + 0][dh];
    float v1 = red[0][n4 + 1][dh] + red[1][n4 + 1][dh] + red[2][n4 + 1][dh] + red[3][n4 + 1][dh];
    float v2 = red[0][n4 + 2][dh] + red[1][n4 + 2][dh] + red[2][n4 + 2][dh] + red[3][n4 + 2][dh];
    float v3 = red[0][n4 + 3][dh] + red[1][n4 + 3][dh] + red[2][n4 + 3][dh] + red[3][n4 + 3][dh];
    o.x = f2bf(v0); o.y = f2bf(v1); o.z = f2bf(v2); o.w = f2bf(v3);
    *(ushort4*)&WhT[((size_t)(bh * DH + dh)) * N + n0 + n4] = o;
}

// Per-row softmax stats over masked e[n,m] = lrelu(src[n]+dst[m]).
__global__ __launch_bounds__(256) void k_rowstats(const unsigned long long* __restrict__ pack,
                                                  const float* __restrict__ srcv,
                                                  const float* __restrict__ dstv,
                                                  float* __restrict__ rowmax,
                                                  float* __restrict__ rowsum) {
    int bn = blockIdx.x;
    int b = bn >> 10, n = bn & 1023;
    int hh = threadIdx.x >> 6, lane = threadIdx.x & 63;
    int bh = b * H + hh;
    const unsigned long long* prow = pack + (size_t)bn * 16;
    const float* dstp = dstv + bh * N;
    float src = srcv[bh * N + n];
    float mx = -1e30f, sum = 0.f;
#pragma unroll
    for (int it = 0; it < N / 64; ++it) {
        int m = lane + it * 64;
        bool mask = (prow[it] >> lane) & 1;
        float e = src + dstp[m];
        e = e > 0.f ? e : 0.2f * e;
        float nm = mask ? fmaxf(mx, e) : mx;
        sum = sum * __expf(mx - nm) + (mask ? __expf(e - nm) : 0.f);
        mx = nm;
    }
#pragma unroll
    for (int off = 32; off; off >>= 1) {
        float mo = __shfl_xor(mx, off, 64);
        float so = __shfl_xor(sum, off, 64);
        float M = fmaxf(mx, mo);
        sum = sum * __expf(mx - M) + so * __expf(mo - M);
        mx = M;
    }
    if (lane == 0) {
        rowmax[bh * N + n] = mx;
        rowsum[bh * N + n] = sum;
    }
}

// h_prime = alpha @ Wh. Block = (bh, 16-row tile); wave w covers m in
// [w*256,(w+1)*256); LDS-reduce 4 partial accumulators.
__global__ __launch_bounds__(256) void k_attn(const unsigned long long* __restrict__ pack,
                                              const float* __restrict__ srcv,
                                              const float* __restrict__ dstv,
                                              const float* __restrict__ rowmax,
                                              const float* __restrict__ rowsum,
                                              const unsigned short* __restrict__ WhT,
                                              float* __restrict__ hp) {
    __shared__ float red[4][16][64];
    int tid = threadIdx.x;
    int bt = blockIdx.x;
    int bh = bt >> 6;
    int n0 = (bt & 63) * 16;
    int b = bh >> 2;
    int w = tid >> 6, lane = tid & 63;
    int rowLane = lane & 15, quad = lane >> 4;
    int n = n0 + rowLane;
    const unsigned char* pb = (const unsigned char*)(pack + ((size_t)(b * N + n)) * 16);
    const float* dq = dstv + bh * N + quad * 8 + w * 256;
    float src = srcv[bh * N + n];
    float mx = rowmax[bh * N + n];
    float inv = 1.0f / rowsum[bh * N + n];
    const unsigned short* wp0 = WhT + ((size_t)(bh * DH + rowLane)) * N + quad * 8 + w * 256;
    const unsigned short* wp1 = wp0 + (size_t)16 * N;
    const unsigned short* wp2 = wp0 + (size_t)32 * N;
    const unsigned short* wp3 = wp0 + (size_t)48 * N;

    f32x4 acc[4] = {};
#pragma unroll
    for (int mt = 0; mt < 4; ++mt) {
#pragma unroll
        for (int kk = 0; kk < 2; ++kk) {
            int mo = mt * 64 + kk * 32;
            unsigned bits = pb[w * 32 + mt * 8 + kk * 4 + quad];
            float4 d0 = *(const float4*)(dq + mo);
            float4 d1 = *(const float4*)(dq + mo + 4);
            float dd[8] = {d0.x, d0.y, d0.z, d0.w, d1.x, d1.y, d1.z, d1.w};
            short8 af;
#pragma unroll
            for (int j = 0; j < 8; ++j) {
                float e = src + dd[j];
                e = e > 0.f ? e : 0.2f * e;
                float p = ((bits >> j) & 1) ? __expf(e - mx) * inv : 0.f;
                af[j] = (short)f2bf(p);
            }
            acc[0] = __builtin_amdgcn_mfma_f32_16x16x32_bf16(af, *(const short8*)(wp0 + mo), acc[0], 0, 0, 0);
            acc[1] = __builtin_amdgcn_mfma_f32_16x16x32_bf16(af, *(const short8*)(wp1 + mo), acc[1], 0, 0, 0);
            acc[2] = __builtin_amdgcn_mfma_f32_16x16x32_bf16(af, *(const short8*)(wp2 + mo), acc[2], 0, 0, 0);
            acc[3] = __builtin_amdgcn_mfma_f32_16x16x32_bf16(af, *(const short8*)(wp3 + mo), acc[3], 0, 0, 0);
        }
    }
#pragma unroll
    for (int c = 0; c < 4; ++c)
#pragma unroll
        for (int r = 0; r < 4; ++r)
            red[w][quad * 4 + r][c * 16 + rowLane] = acc[c][r];
    __syncthreads();
    int row = tid >> 4, col4 = (tid & 15) * 4;
    float4 s = make_float4(0.f, 0.f, 0.f, 0.f);
#pragma unroll
    for (int ww = 0; ww < 4; ++ww) {
        float4 v = *(const float4*)&red[ww][row][col4];
        s.x += v.x; s.y += v.y; s.z += v.z; s.w += v.w;
    }
    *(float4*)&hp[((size_t)bh * N + n0 + row) * DH + col4] = s;
}

// out = LN(h + concat(hp)); emit bf16 copy + next layer's src/dst projections.
__global__ __launch_bounds__(256) void k_ln(const float* __restrict__ h,
                                            const float* __restrict__ hp,
                                            const float* __restrict__ scale,
                                            const float* __restrict__ bias,
                                            float* __restrict__ out,
                                            unsigned short* __restrict__ out_bf,
                                            const float* __restrict__ wa_src,
                                            const float* __restrict__ wa_dst,
                                            float* __restrict__ srcv,
                                            float* __restrict__ dstv,
                                            int layer, int has_next) {
    __shared__ float red[8];
    __shared__ float red2[8][4];
    int bn = blockIdx.x;
    int b = bn >> 10, n = bn & 1023;
    int c = threadIdx.x;
    int hh = c >> 6, k = c & 63;
    float x = h[(size_t)bn * D + c] + hp[((size_t)(b * H + hh) * N + n) * DH + k];
    float s = x, s2 = x * x;
#pragma unroll
    for (int off = 32; off; off >>= 1) {
        s += __shfl_xor(s, off, 64);
        s2 += __shfl_xor(s2, off, 64);
    }
    int w = c >> 6, lane = c & 63;
    if (lane == 0) { red[w] = s; red[4 + w] = s2; }
    __syncthreads();
    s = red[0] + red[1] + red[2] + red[3];
    s2 = red[4] + red[5] + red[6] + red[7];
    float mu = s * (1.0f / D);
    float var = s2 * (1.0f / D) - mu * mu;
    float r = rsqrtf(var + 1e-5f);
    float y = (x - mu) * r * scale[layer * D + c] + bias[layer * D + c];
    out[(size_t)bn * D + c] = y;
    if (has_next) {
        out_bf[(size_t)bn * D + c] = f2bf(y);
        float sv[4], dv[4];
#pragma unroll
        for (int h2 = 0; h2 < H; ++h2) {
            sv[h2] = y * wa_src[h2 * D + c];
            dv[h2] = y * wa_dst[h2 * D + c];
        }
#pragma unroll
        for (int off = 32; off; off >>= 1) {
#pragma unroll
            for (int h2 = 0; h2 < H; ++h2) {
                sv[h2] += __shfl_xor(sv[h2], off, 64);
                dv[h2] += __shfl_xor(dv[h2], off, 64);
            }
        }
        if (lane < 4) red2[lane][w] = sv[lane];
        else if (lane < 8) red2[lane][w] = dv[lane - 4];
        __syncthreads();
        if (c < 8) {
            float v = red2[c][0] + red2[c][1] + red2[c][2] + red2[c][3];
            int h2 = c & 3;
            if (c < 4) srcv[(b * H + h2) * N + n] = v;
            else dstv[(b * H + h2) * N + n] = v;
        }
    }
}

__global__ void k_len(const int* __restrict__ len, float* __restrict__ out) {
    int i = threadIdx.x;
    if (i < B) out[i] = (float)len[i];
}

extern "C" void kernel_launch(void* const* d_in, const int* in_sizes, int n_in,
                              void* d_out, int out_size, void* d_ws, size_t ws_size,
                              hipStream_t stream) {
    const int* cfg_adj = (const int*)d_in[0];
    const int* cfg_nodes = (const int*)d_in[1];
    const int* cfg_len = (const int*)d_in[2];
    const float* emb = (const float*)d_in[3];
    const float* W = (const float*)d_in[4];
    const float* a_src = (const float*)d_in[5];
    const float* a_dst = (const float*)d_in[6];
    const float* ln_scale = (const float*)d_in[7];
    const float* ln_bias = (const float*)d_in[8];
    float* out = (float*)d_out;
    float* ws = (float*)d_ws;

    float* h = ws;
    float* hp = h + (size_t)B * N * D;
    float* srcv = hp + (size_t)B * H * N * DH;
    float* dstv = srcv + (size_t)B * H * N;
    float* rowmax = dstv + (size_t)B * H * N;
    float* rowsum = rowmax + (size_t)B * H * N;
    unsigned short* h_bf = (unsigned short*)(rowsum + (size_t)B * H * N);
    unsigned short* WhT = h_bf + (size_t)B * N * D;
    unsigned short* WT_bf = WhT + (size_t)B * H * DH * N;
    float* wa_src = (float*)(WT_bf + (size_t)NLAYERS * H * DH * D);
    float* wa_dst = wa_src + NLAYERS * H * D;
    unsigned long long* pack = (unsigned long long*)(wa_dst + NLAYERS * H * D);

    k_wprep<<<dim3(NLAYERS * H, 4), 256, 0, stream>>>(W, a_src, a_dst, WT_bf, wa_src, wa_dst);
    k_packadj<<<B * N / 4, 256, 0, stream>>>(cfg_adj, pack);
    k_nodefeat<<<B * N / 4, 256, 0, stream>>>(cfg_nodes, emb, wa_src, wa_dst, h, h_bf, srcv, dstv);
    for (int l = 0; l < NLAYERS; ++l) {
        k_rowstats<<<B * N, 256, 0, stream>>>(pack, srcv, dstv, rowmax, rowsum);
        k_wh<<<dim3(B * 64, H), 256, 0, stream>>>(h_bf, WT_bf + (size_t)l * H * DH * D, WhT);
        k_attn<<<B * H * 64, 256, 0, stream>>>(pack, srcv, dstv, rowmax, rowsum, WhT, hp);
        k_ln<<<B * N, 256, 0, stream>>>(h, hp, ln_scale, ln_bias,
                                        (l == NLAYERS - 1) ? out : h, h_bf,
                                        wa_src + (size_t)(l + 1) * H * D,
                                        wa_dst + (size_t)(l + 1) * H * D,
                                        srcv, dstv, l, l < NLAYERS - 1 ? 1 : 0);
    }
    k_len<<<1, 64, 0, stream>>>(cfg_len, out + (size_t)B * N * D);
}

// Round 5
// 250.625 us; speedup vs baseline: 1.5890x; 1.3211x over previous
//
#include <hip/hip_runtime.h>
#include <math.h>

#define B 8
#define N 1024
#define L 16
#define D 256
#define H 4
#define DH 64
#define NLAYERS 2

typedef __attribute__((ext_vector_type(8))) short short8;
typedef __attribute__((ext_vector_type(4))) float f32x4;

__device__ inline unsigned short f2bf(float x) {
    unsigned u = __float_as_uint(x);
    u = (u + 0x7fff + ((u >> 16) & 1)) >> 16;  // RNE
    return (unsigned short)u;
}

// -------- swizzled layouts --------
// h_sw  [b][n>>4][d>>5][n&15][d&31]    bf16  (A-operand of k_wh)
// WT_sw [lh][d>>5][dh][d&31]           bf16  (B-operand of k_wh)
// WhT_sw[bh][m>>5][dh][m&31]           bf16  (B-operand of k_attn; m = source node)
// pack  [b][n][m/64]                   u64 adjacency bitmask (+self-loop)

// ---- pre1: packadj (2048 blocks) + wprep (32 blocks) + len (1 block) ----
__global__ __launch_bounds__(256) void k_pre1(const int* __restrict__ adj,
                                              const float* __restrict__ W,
                                              const float* __restrict__ a_src,
                                              const float* __restrict__ a_dst,
                                              const int* __restrict__ len,
                                              unsigned long long* __restrict__ pack,
                                              unsigned short* __restrict__ WT_sw,
                                              float* __restrict__ wa_src,
                                              float* __restrict__ wa_dst,
                                              float* __restrict__ out_len) {
    int bid = blockIdx.x;
    int t = threadIdx.x;
    if (bid < 2048) {
        // pack adjacency
        int row = bid * 4 + (t >> 6);  // bn
        int lane = t & 63;
        int n = row & (N - 1);
        const int* arow = adj + (long)row * N;
        unsigned long long* prow = pack + (size_t)row * 16;
#pragma unroll
        for (int it = 0; it < 16; ++it) {
            int m = lane + it * 64;
            unsigned long long bits = __ballot(arow[m] != 0 || m == n);
            if (lane == 0) prow[it] = bits;
        }
    } else if (bid < 2048 + NLAYERS * H * 4) {
        int idx = bid - 2048;
        int lh = idx >> 2, q = idx & 3;
        const float* Wl = W + (size_t)lh * D * DH;
        int dh = t & 63;
        int d0 = q * 64 + (t >> 6) * 16;
#pragma unroll
        for (int i = 0; i < 16; ++i) {
            int d = d0 + i;
            WT_sw[(((size_t)lh * 8 + (d >> 5)) * 64 + dh) * 32 + (d & 31)] = f2bf(Wl[(size_t)d * DH + dh]);
        }
        if (q == 0) {
            const float* as = a_src + lh * DH;
            const float* ad = a_dst + lh * DH;
            float s = 0.f, dd = 0.f;
#pragma unroll 8
            for (int k = 0; k < DH; ++k) {
                float w = Wl[(size_t)t * DH + k];
                s += w * as[k];
                dd += w * ad[k];
            }
            wa_src[lh * D + t] = s;
            wa_dst[lh * D + t] = dd;
        }
    } else {
        if (t < B) out_len[t] = (float)len[t];
    }
}

// ---- pre2: node_feat (mean emb) + fused layer-0 src/dst projections ----
__global__ __launch_bounds__(256) void k_nodefeat(const int* __restrict__ nodes,
                                                  const float* __restrict__ emb,
                                                  const float* __restrict__ wa_src,
                                                  const float* __restrict__ wa_dst,
                                                  float* __restrict__ h,
                                                  unsigned short* __restrict__ h_sw,
                                                  float* __restrict__ srcv,
                                                  float* __restrict__ dstv) {
    int bn = blockIdx.x * 4 + (threadIdx.x >> 6);
    int lane = threadIdx.x & 63;
    int d4 = lane * 4;
    const int* np = nodes + bn * L;
    float4 s = make_float4(0.f, 0.f, 0.f, 0.f);
#pragma unroll
    for (int l = 0; l < L; ++l) {
        float4 v = *(const float4*)&emb[(size_t)np[l] * D + d4];
        s.x += v.x; s.y += v.y; s.z += v.z; s.w += v.w;
    }
    s.x *= (1.0f / L); s.y *= (1.0f / L); s.z *= (1.0f / L); s.w *= (1.0f / L);
    *(float4*)&h[(size_t)bn * D + d4] = s;
    int b = bn >> 10, n = bn & 1023;
    ushort4 bv;
    bv.x = f2bf(s.x); bv.y = f2bf(s.y); bv.z = f2bf(s.z); bv.w = f2bf(s.w);
    *(ushort4*)&h_sw[(((size_t)b * 64 + (n >> 4)) * 8 + (d4 >> 5)) * 512 + (n & 15) * 32 + (d4 & 31)] = bv;
    // fused src/dst for layer 0
    float sv[4], dv[4];
#pragma unroll
    for (int hh = 0; hh < H; ++hh) {
        float4 ws = *(const float4*)&wa_src[hh * D + d4];
        float4 wd = *(const float4*)&wa_dst[hh * D + d4];
        sv[hh] = s.x * ws.x + s.y * ws.y + s.z * ws.z + s.w * ws.w;
        dv[hh] = s.x * wd.x + s.y * wd.y + s.z * wd.z + s.w * wd.w;
    }
#pragma unroll
    for (int off = 32; off; off >>= 1) {
#pragma unroll
        for (int hh = 0; hh < H; ++hh) {
            sv[hh] += __shfl_xor(sv[hh], off, 64);
            dv[hh] += __shfl_xor(dv[hh], off, 64);
        }
    }
    if (lane == 0) {
#pragma unroll
        for (int hh = 0; hh < H; ++hh) {
            srcv[(b * H + hh) * N + n] = sv[hh];
            dstv[(b * H + hh) * N + n] = dv[hh];
        }
    }
}

// ---- k_wh: WhT_sw = (h @ W)^T via MFMA, split-K across waves ----
__global__ __launch_bounds__(256) void k_wh(const unsigned short* __restrict__ h_sw,
                                            const unsigned short* __restrict__ WT_l,
                                            unsigned short* __restrict__ WhT) {
    __shared__ float red[4][16][68];
    int bt = blockIdx.x;   // b*64 + nt
    int hh = blockIdx.y;
    int b = bt >> 6;
    int nt = bt & 63;
    int n0 = nt * 16;
    int tid = threadIdx.x;
    int w = tid >> 6, lane = tid & 63;
    int rowLane = lane & 15, quad = lane >> 4;
    int bh = b * H + hh;
    const unsigned short* abase = h_sw + (((size_t)b * 64 + nt) * 8) * 512 + rowLane * 32 + quad * 8;
    const unsigned short* bbase = WT_l + ((size_t)hh * 8) * 2048 + rowLane * 32 + quad * 8;
    f32x4 acc[4] = {};
#pragma unroll
    for (int kk = 0; kk < 2; ++kk) {
        int kc = w * 2 + kk;
        short8 af = *(const short8*)(abase + kc * 512);
#pragma unroll
        for (int c = 0; c < 4; ++c) {
            short8 bf = *(const short8*)(bbase + kc * 2048 + c * 512);
            acc[c] = __builtin_amdgcn_mfma_f32_16x16x32_bf16(af, bf, acc[c], 0, 0, 0);
        }
    }
#pragma unroll
    for (int c = 0; c < 4; ++c)
#pragma unroll
        for (int r = 0; r < 4; ++r)
            red[w][quad * 4 + r][c * 16 + rowLane] = acc[c][r];
    __syncthreads();
    // epilogue: thread (dh = tid>>2, j4 = tid&3) writes 4 consecutive n
    int dh = tid >> 2, j4 = tid & 3;
    float v[4];
#pragma unroll
    for (int i = 0; i < 4; ++i)
        v[i] = red[0][j4 * 4 + i][dh] + red[1][j4 * 4 + i][dh] + red[2][j4 * 4 + i][dh] + red[3][j4 * 4 + i][dh];
    ushort4 o;
    o.x = f2bf(v[0]); o.y = f2bf(v[1]); o.z = f2bf(v[2]); o.w = f2bf(v[3]);
    *(ushort4*)&WhT[(((size_t)bh * 32 + (n0 >> 5)) * 64 + dh) * 32 + (n0 & 31) + j4 * 4] = o;
}

// ---- k_attn: fused rowstats + alpha@Wh (MFMA) ----
// Block = (bh, 16-row n-tile). Wave w owns m-slab [w*256,(w+1)*256).
__global__ __launch_bounds__(256) void k_attn(const unsigned long long* __restrict__ pack,
                                              const float* __restrict__ srcv,
                                              const float* __restrict__ dstv,
                                              const unsigned short* __restrict__ WhT,
                                              float* __restrict__ hp) {
    __shared__ float red[4][16][68];     // 17.4 KB; first 1024 floats alias dsts[4][256]
    __shared__ float smx[4][16], ssum[4][16];
    float* dsts = &red[0][0][0];

    int tid = threadIdx.x;
    int bt = blockIdx.x;
    int bh = bt >> 6;
    int n0 = (bt & 63) * 16;
    int b = bh >> 2;
    int w = tid >> 6, lane = tid & 63;
    int rowLane = lane & 15, quad = lane >> 4;
    int n = n0 + rowLane;

    // stage dst slab (coalesced) + per-row loads
    {
        float4 v = *(const float4*)(dstv + bh * N + w * 256 + lane * 4);
        *(float4*)(dsts + w * 256 + lane * 4) = v;
    }
    unsigned long long pst = pack[((size_t)(b * N + n)) * 16 + w * 4 + quad];
    const uint4* pbp = (const uint4*)((const unsigned char*)(pack + ((size_t)(b * N + n)) * 16) + w * 32);
    uint4 pbv0 = pbp[0];
    uint4 pbv1 = pbp[1];
    float src = srcv[bh * N + n];
    __syncthreads();

    // pass 1: masked max of dst (lrelu monotone => rowmax = lrelu(src+maxd))
    float maxd = -1e30f;
#pragma unroll
    for (int i4 = 0; i4 < 16; ++i4) {
        float4 dv = *(const float4*)(dsts + w * 256 + quad * 64 + i4 * 4);
        float dd[4] = {dv.x, dv.y, dv.z, dv.w};
#pragma unroll
        for (int j = 0; j < 4; ++j) {
            bool msk = (pst >> (i4 * 4 + j)) & 1;
            maxd = msk ? fmaxf(maxd, dd[j]) : maxd;
        }
    }
    maxd = fmaxf(maxd, __shfl_xor(maxd, 16, 64));
    maxd = fmaxf(maxd, __shfl_xor(maxd, 32, 64));
    if (quad == 0) smx[w][rowLane] = maxd;
    __syncthreads();
    maxd = fmaxf(fmaxf(smx[0][rowLane], smx[1][rowLane]), fmaxf(smx[2][rowLane], smx[3][rowLane]));
    float e0 = src + maxd;
    float mx = e0 > 0.f ? e0 : 0.2f * e0;

    // pass 2: masked exp-sum
    float sum = 0.f;
#pragma unroll
    for (int i4 = 0; i4 < 16; ++i4) {
        float4 dv = *(const float4*)(dsts + w * 256 + quad * 64 + i4 * 4);
        float dd[4] = {dv.x, dv.y, dv.z, dv.w};
#pragma unroll
        for (int j = 0; j < 4; ++j) {
            bool msk = (pst >> (i4 * 4 + j)) & 1;
            float e = src + dd[j];
            e = e > 0.f ? e : 0.2f * e;
            sum += msk ? __expf(e - mx) : 0.f;
        }
    }
    sum += __shfl_xor(sum, 16, 64);
    sum += __shfl_xor(sum, 32, 64);
    if (quad == 0) ssum[w][rowLane] = sum;
    __syncthreads();
    sum = ssum[0][rowLane] + ssum[1][rowLane] + ssum[2][rowLane] + ssum[3][rowLane];
    float inv = 1.0f / sum;

    // phase B: MFMA over this wave's m-slab; B-frags fully coalesced (swizzled)
    unsigned words[8] = {pbv0.x, pbv0.y, pbv0.z, pbv0.w, pbv1.x, pbv1.y, pbv1.z, pbv1.w};
    const unsigned short* wbase = WhT + ((size_t)bh * 32) * 2048 + rowLane * 32 + quad * 8;
    f32x4 acc[4] = {};
#pragma unroll
    for (int mt = 0; mt < 4; ++mt) {
#pragma unroll
        for (int kk = 0; kk < 2; ++kk) {
            int tile = w * 8 + mt * 2 + kk;
            unsigned bits = (words[mt * 2 + kk] >> (quad * 8)) & 0xffu;
            float4 d0 = *(const float4*)(dsts + w * 256 + mt * 64 + kk * 32 + quad * 8);
            float4 d1 = *(const float4*)(dsts + w * 256 + mt * 64 + kk * 32 + quad * 8 + 4);
            float dd[8] = {d0.x, d0.y, d0.z, d0.w, d1.x, d1.y, d1.z, d1.w};
            short8 af;
#pragma unroll
            for (int j = 0; j < 8; ++j) {
                float e = src + dd[j];
                e = e > 0.f ? e : 0.2f * e;
                float p = ((bits >> j) & 1) ? __expf(e - mx) * inv : 0.f;
                af[j] = (short)f2bf(p);
            }
            const unsigned short* tb = wbase + (size_t)tile * 2048;
            acc[0] = __builtin_amdgcn_mfma_f32_16x16x32_bf16(af, *(const short8*)(tb + 0 * 512), acc[0], 0, 0, 0);
            acc[1] = __builtin_amdgcn_mfma_f32_16x16x32_bf16(af, *(const short8*)(tb + 1 * 512), acc[1], 0, 0, 0);
            acc[2] = __builtin_amdgcn_mfma_f32_16x16x32_bf16(af, *(const short8*)(tb + 2 * 512), acc[2], 0, 0, 0);
            acc[3] = __builtin_amdgcn_mfma_f32_16x16x32_bf16(af, *(const short8*)(tb + 3 * 512), acc[3], 0, 0, 0);
        }
    }
    __syncthreads();  // dsts dead; red may now overwrite
#pragma unroll
    for (int c = 0; c < 4; ++c)
#pragma unroll
        for (int r = 0; r < 4; ++r)
            red[w][quad * 4 + r][c * 16 + rowLane] = acc[c][r];
    __syncthreads();
    int row = tid >> 4, col4 = (tid & 15) * 4;
    float4 s = make_float4(0.f, 0.f, 0.f, 0.f);
#pragma unroll
    for (int ww = 0; ww < 4; ++ww) {
        float4 v = *(const float4*)&red[ww][row][col4];
        s.x += v.x; s.y += v.y; s.z += v.z; s.w += v.w;
    }
    *(float4*)&hp[((size_t)bh * N + n0 + row) * DH + col4] = s;
}

// ---- k_ln: LN(h + concat(hp)); emits swizzled bf16 + next-layer src/dst ----
__global__ __launch_bounds__(256) void k_ln(const float* __restrict__ h,
                                            const float* __restrict__ hp,
                                            const float* __restrict__ scale,
                                            const float* __restrict__ bias,
                                            float* __restrict__ out,
                                            unsigned short* __restrict__ h_sw,
                                            const float* __restrict__ wa_src,
                                            const float* __restrict__ wa_dst,
                                            float* __restrict__ srcv,
                                            float* __restrict__ dstv,
                                            int layer, int has_next) {
    __shared__ float red[8];
    __shared__ float red2[8][4];
    int bn = blockIdx.x;
    int b = bn >> 10, n = bn & 1023;
    int c = threadIdx.x;
    int hh = c >> 6, k = c & 63;
    float x = h[(size_t)bn * D + c] + hp[((size_t)(b * H + hh) * N + n) * DH + k];
    float s = x, s2 = x * x;
#pragma unroll
    for (int off = 32; off; off >>= 1) {
        s += __shfl_xor(s, off, 64);
        s2 += __shfl_xor(s2, off, 64);
    }
    int w = c >> 6, lane = c & 63;
    if (lane == 0) { red[w] = s; red[4 + w] = s2; }
    __syncthreads();
    s = red[0] + red[1] + red[2] + red[3];
    s2 = red[4] + red[5] + red[6] + red[7];
    float mu = s * (1.0f / D);
    float var = s2 * (1.0f / D) - mu * mu;
    float r = rsqrtf(var + 1e-5f);
    float y = (x - mu) * r * scale[layer * D + c] + bias[layer * D + c];
    out[(size_t)bn * D + c] = y;
    if (has_next) {
        h_sw[(((size_t)b * 64 + (n >> 4)) * 8 + (c >> 5)) * 512 + (n & 15) * 32 + (c & 31)] = f2bf(y);
        float sv[4], dv[4];
#pragma unroll
        for (int h2 = 0; h2 < H; ++h2) {
            sv[h2] = y * wa_src[h2 * D + c];
            dv[h2] = y * wa_dst[h2 * D + c];
        }
#pragma unroll
        for (int off = 32; off; off >>= 1) {
#pragma unroll
            for (int h2 = 0; h2 < H; ++h2) {
                sv[h2] += __shfl_xor(sv[h2], off, 64);
                dv[h2] += __shfl_xor(dv[h2], off, 64);
            }
        }
        if (lane < 4) red2[lane][w] = sv[lane];
        else if (lane < 8) red2[lane][w] = dv[lane - 4];
        __syncthreads();
        if (c < 8) {
            float v = red2[c][0] + red2[c][1] + red2[c][2] + red2[c][3];
            int h2 = c & 3;
            if (c < 4) srcv[(b * H + h2) * N + n] = v;
            else dstv[(b * H + h2) * N + n] = v;
        }
    }
}

extern "C" void kernel_launch(void* const* d_in, const int* in_sizes, int n_in,
                              void* d_out, int out_size, void* d_ws, size_t ws_size,
                              hipStream_t stream) {
    const int* cfg_adj = (const int*)d_in[0];
    const int* cfg_nodes = (const int*)d_in[1];
    const int* cfg_len = (const int*)d_in[2];
    const float* emb = (const float*)d_in[3];
    const float* W = (const float*)d_in[4];
    const float* a_src = (const float*)d_in[5];
    const float* a_dst = (const float*)d_in[6];
    const float* ln_scale = (const float*)d_in[7];
    const float* ln_bias = (const float*)d_in[8];
    float* out = (float*)d_out;
    float* ws = (float*)d_ws;

    float* h = ws;
    float* hp = h + (size_t)B * N * D;
    float* srcv = hp + (size_t)B * H * N * DH;
    float* dstv = srcv + (size_t)B * H * N;
    unsigned short* h_sw = (unsigned short*)(dstv + (size_t)B * H * N);
    unsigned short* WhT = h_sw + (size_t)B * N * D;
    unsigned short* WT_sw = WhT + (size_t)B * H * DH * N;
    float* wa_src = (float*)(WT_sw + (size_t)NLAYERS * H * DH * D);
    float* wa_dst = wa_src + NLAYERS * H * D;
    unsigned long long* pack = (unsigned long long*)(wa_dst + NLAYERS * H * D);

    k_pre1<<<2048 + NLAYERS * H * 4 + 1, 256, 0, stream>>>(
        cfg_adj, W, a_src, a_dst, cfg_len, pack, WT_sw, wa_src, wa_dst,
        out + (size_t)B * N * D);
    k_nodefeat<<<B * N / 4, 256, 0, stream>>>(cfg_nodes, emb, wa_src, wa_dst, h, h_sw, srcv, dstv);
    for (int l = 0; l < NLAYERS; ++l) {
        k_wh<<<dim3(B * 64, H), 256, 0, stream>>>(h_sw, WT_sw + (size_t)l * H * 8 * 2048, WhT);
        k_attn<<<B * H * 64, 256, 0, stream>>>(pack, srcv, dstv, WhT, hp);
        k_ln<<<B * N, 256, 0, stream>>>(h, hp, ln_scale, ln_bias,
                                        (l == NLAYERS - 1) ? out : h, h_sw,
                                        wa_src + (size_t)(l + 1) * H * D,
                                        wa_dst + (size_t)(l + 1) * H * D,
                                        srcv, dstv, l, l < NLAYERS - 1 ? 1 : 0);
    }
}

// Round 7
// 234.857 us; speedup vs baseline: 1.6957x; 1.0671x over previous
//
#include <hip/hip_runtime.h>
#include <math.h>

#define B 8
#define N 1024
#define L 16
#define D 256
#define H 4
#define DH 64
#define NLAYERS 2

typedef __attribute__((ext_vector_type(8))) short short8;
typedef __attribute__((ext_vector_type(4))) float f32x4;

__device__ inline unsigned short f2bf(float x) {
    unsigned u = __float_as_uint(x);
    u = (u + 0x7fff + ((u >> 16) & 1)) >> 16;  // RNE
    return (unsigned short)u;
}

// -------- swizzled layouts --------
// h_sw  [b][n>>4][d>>5][n&15][d&31]    bf16  (A-operand of k_wh)
// WT_sw [lh][d>>5][dh][d&31]           bf16  (B-operand of k_wh)
// WhT_sw[bh][m>>5][dh][m&31]           bf16  (B-operand of k_attn; m = source node)
// pack  [b][n][m/64]                   u64 adjacency bitmask (+self-loop)

// ---- pre1: packadj (2048 blocks) + wprep (32 blocks) + len (1 block) ----
__global__ __launch_bounds__(256) void k_pre1(const int* __restrict__ adj,
                                              const float* __restrict__ W,
                                              const float* __restrict__ a_src,
                                              const float* __restrict__ a_dst,
                                              const int* __restrict__ len,
                                              unsigned long long* __restrict__ pack,
                                              unsigned short* __restrict__ WT_sw,
                                              float* __restrict__ wa_src,
                                              float* __restrict__ wa_dst,
                                              float* __restrict__ out_len) {
    int bid = blockIdx.x;
    int t = threadIdx.x;
    if (bid < 2048) {
        int row = bid * 4 + (t >> 6);  // bn
        int lane = t & 63;
        int n = row & (N - 1);
        const int* arow = adj + (long)row * N;
        unsigned long long* prow = pack + (size_t)row * 16;
#pragma unroll
        for (int it = 0; it < 16; ++it) {
            int m = lane + it * 64;
            unsigned long long bits = __ballot(arow[m] != 0 || m == n);
            if (lane == 0) prow[it] = bits;
        }
    } else if (bid < 2048 + NLAYERS * H * 4) {
        int idx = bid - 2048;
        int lh = idx >> 2, q = idx & 3;
        const float* Wl = W + (size_t)lh * D * DH;
        int dh = t & 63;
        int d0 = q * 64 + (t >> 6) * 16;
#pragma unroll
        for (int i = 0; i < 16; ++i) {
            int d = d0 + i;
            WT_sw[(((size_t)lh * 8 + (d >> 5)) * 64 + dh) * 32 + (d & 31)] = f2bf(Wl[(size_t)d * DH + dh]);
        }
        if (q == 0) {
            const float* as = a_src + lh * DH;
            const float* ad = a_dst + lh * DH;
            float s = 0.f, dd = 0.f;
#pragma unroll 8
            for (int k = 0; k < DH; ++k) {
                float w = Wl[(size_t)t * DH + k];
                s += w * as[k];
                dd += w * ad[k];
            }
            wa_src[lh * D + t] = s;
            wa_dst[lh * D + t] = dd;
        }
    } else {
        if (t < B) out_len[t] = (float)len[t];
    }
}

// ---- pre2: node_feat (mean emb) + fused layer-0 src/dst projections ----
__global__ __launch_bounds__(256) void k_nodefeat(const int* __restrict__ nodes,
                                                  const float* __restrict__ emb,
                                                  const float* __restrict__ wa_src,
                                                  const float* __restrict__ wa_dst,
                                                  float* __restrict__ h,
                                                  unsigned short* __restrict__ h_sw,
                                                  float* __restrict__ srcv,
                                                  float* __restrict__ dstv) {
    int bn = blockIdx.x * 4 + (threadIdx.x >> 6);
    int lane = threadIdx.x & 63;
    int d4 = lane * 4;
    const int* np = nodes + bn * L;
    float4 s = make_float4(0.f, 0.f, 0.f, 0.f);
#pragma unroll
    for (int l = 0; l < L; ++l) {
        float4 v = *(const float4*)&emb[(size_t)np[l] * D + d4];
        s.x += v.x; s.y += v.y; s.z += v.z; s.w += v.w;
    }
    s.x *= (1.0f / L); s.y *= (1.0f / L); s.z *= (1.0f / L); s.w *= (1.0f / L);
    *(float4*)&h[(size_t)bn * D + d4] = s;
    int b = bn >> 10, n = bn & 1023;
    ushort4 bv;
    bv.x = f2bf(s.x); bv.y = f2bf(s.y); bv.z = f2bf(s.z); bv.w = f2bf(s.w);
    *(ushort4*)&h_sw[(((size_t)b * 64 + (n >> 4)) * 8 + (d4 >> 5)) * 512 + (n & 15) * 32 + (d4 & 31)] = bv;
    float sv[4], dv[4];
#pragma unroll
    for (int hh = 0; hh < H; ++hh) {
        float4 ws = *(const float4*)&wa_src[hh * D + d4];
        float4 wd = *(const float4*)&wa_dst[hh * D + d4];
        sv[hh] = s.x * ws.x + s.y * ws.y + s.z * ws.z + s.w * ws.w;
        dv[hh] = s.x * wd.x + s.y * wd.y + s.z * wd.z + s.w * wd.w;
    }
#pragma unroll
    for (int off = 32; off; off >>= 1) {
#pragma unroll
        for (int hh = 0; hh < H; ++hh) {
            sv[hh] += __shfl_xor(sv[hh], off, 64);
            dv[hh] += __shfl_xor(dv[hh], off, 64);
        }
    }
    if (lane == 0) {
#pragma unroll
        for (int hh = 0; hh < H; ++hh) {
            srcv[(b * H + hh) * N + n] = sv[hh];
            dstv[(b * H + hh) * N + n] = dv[hh];
        }
    }
}

// ---- k_wh: WhT_sw = (h @ W)^T via MFMA, split-K across waves ----
__global__ __launch_bounds__(256) void k_wh(const unsigned short* __restrict__ h_sw,
                                            const unsigned short* __restrict__ WT_l,
                                            unsigned short* __restrict__ WhT) {
    __shared__ float red[4][16][68];
    int bt = blockIdx.x;   // b*64 + nt
    int hh = blockIdx.y;
    int b = bt >> 6;
    int nt = bt & 63;
    int n0 = nt * 16;
    int tid = threadIdx.x;
    int w = tid >> 6, lane = tid & 63;
    int rowLane = lane & 15, quad = lane >> 4;
    int bh = b * H + hh;
    const unsigned short* abase = h_sw + (((size_t)b * 64 + nt) * 8) * 512 + rowLane * 32 + quad * 8;
    const unsigned short* bbase = WT_l + ((size_t)hh * 8) * 2048 + rowLane * 32 + quad * 8;
    f32x4 acc[4] = {};
#pragma unroll
    for (int kk = 0; kk < 2; ++kk) {
        int kc = w * 2 + kk;
        short8 af = *(const short8*)(abase + kc * 512);
#pragma unroll
        for (int c = 0; c < 4; ++c) {
            short8 bf = *(const short8*)(bbase + kc * 2048 + c * 512);
            acc[c] = __builtin_amdgcn_mfma_f32_16x16x32_bf16(af, bf, acc[c], 0, 0, 0);
        }
    }
#pragma unroll
    for (int c = 0; c < 4; ++c)
#pragma unroll
        for (int r = 0; r < 4; ++r)
            red[w][quad * 4 + r][c * 16 + rowLane] = acc[c][r];
    __syncthreads();
    int dh = tid >> 2, j4 = tid & 3;
    float v[4];
#pragma unroll
    for (int i = 0; i < 4; ++i)
        v[i] = red[0][j4 * 4 + i][dh] + red[1][j4 * 4 + i][dh] + red[2][j4 * 4 + i][dh] + red[3][j4 * 4 + i][dh];
    ushort4 o;
    o.x = f2bf(v[0]); o.y = f2bf(v[1]); o.z = f2bf(v[2]); o.w = f2bf(v[3]);
    *(ushort4*)&WhT[(((size_t)bh * 32 + (n0 >> 5)) * 64 + dh) * 32 + (n0 & 31) + j4 * 4] = o;
}

// ---- k_attn: fused rowstats + alpha@Wh with DEFERRED NORMALIZATION ----
// h'[n,:] = (sum_m p~[n,m]·Wh[m,:]) / S[n], p~ = exp(lrelu(e)-mx) masked.
// Block = (bh, 16-row n-tile). Wave w owns m-slab [w*256,(w+1)*256).
__global__ __launch_bounds__(256) void k_attn(const unsigned long long* __restrict__ pack,
                                              const float* __restrict__ srcv,
                                              const float* __restrict__ dstv,
                                              const unsigned short* __restrict__ WhT,
                                              float* __restrict__ hp) {
    __shared__ float red[4][16][68];     // 17.4 KB; first 1024 floats alias dsts[4][256]
    __shared__ float smx[4][16], ssum[4][16];
    float* dsts = &red[0][0][0];

    int tid = threadIdx.x;
    int bt = blockIdx.x;
    int bh = bt >> 6;
    int n0 = (bt & 63) * 16;
    int b = bh >> 2;
    int w = tid >> 6, lane = tid & 63;
    int rowLane = lane & 15, quad = lane >> 4;
    int n = n0 + rowLane;

    // stage own wave's dst slab (wave-local: no barrier needed before reading)
    {
        float4 v = *(const float4*)(dstv + bh * N + w * 256 + lane * 4);
        *(float4*)(dsts + w * 256 + lane * 4) = v;
    }
    unsigned long long pst = pack[((size_t)(b * N + n)) * 16 + w * 4 + quad];
    const uint4* pbp = (const uint4*)((const unsigned char*)(pack + ((size_t)(b * N + n)) * 16) + w * 32);
    uint4 pbv0 = pbp[0];
    uint4 pbv1 = pbp[1];
    float src = srcv[bh * N + n];

    // pass 1: masked max of dst (lrelu monotone => rowmax = lrelu(src+maxd))
    float maxd = -1e30f;
#pragma unroll
    for (int i4 = 0; i4 < 16; ++i4) {
        float4 dv = *(const float4*)(dsts + w * 256 + quad * 64 + i4 * 4);
        float dd[4] = {dv.x, dv.y, dv.z, dv.w};
#pragma unroll
        for (int j = 0; j < 4; ++j) {
            bool msk = (pst >> (i4 * 4 + j)) & 1;
            maxd = msk ? fmaxf(maxd, dd[j]) : maxd;
        }
    }
    maxd = fmaxf(maxd, __shfl_xor(maxd, 16, 64));
    maxd = fmaxf(maxd, __shfl_xor(maxd, 32, 64));
    if (quad == 0) smx[w][rowLane] = maxd;
    __syncthreads();
    maxd = fmaxf(fmaxf(smx[0][rowLane], smx[1][rowLane]), fmaxf(smx[2][rowLane], smx[3][rowLane]));
    float e0 = src + maxd;
    float mx = e0 > 0.f ? e0 : 0.2f * e0;

    // fused pass: build unnormalized alpha A-frags, accumulate S, MFMA
    unsigned words[8] = {pbv0.x, pbv0.y, pbv0.z, pbv0.w, pbv1.x, pbv1.y, pbv1.z, pbv1.w};
    const unsigned short* wbase = WhT + ((size_t)bh * 32) * 2048 + rowLane * 32 + quad * 8;
    f32x4 acc[4] = {};
    float sum = 0.f;
#pragma unroll
    for (int t2 = 0; t2 < 8; ++t2) {
        unsigned bits = (words[t2] >> (quad * 8)) & 0xffu;
        float4 d0 = *(const float4*)(dsts + w * 256 + t2 * 32 + quad * 8);
        float4 d1 = *(const float4*)(dsts + w * 256 + t2 * 32 + quad * 8 + 4);
        float dd[8] = {d0.x, d0.y, d0.z, d0.w, d1.x, d1.y, d1.z, d1.w};
        short8 af;
#pragma unroll
        for (int j = 0; j < 8; ++j) {
            float e = src + dd[j];
            e = e > 0.f ? e : 0.2f * e;
            float p = ((bits >> j) & 1) ? __expf(e - mx) : 0.f;
            sum += p;
            af[j] = (short)f2bf(p);
        }
        const unsigned short* tb = wbase + (size_t)(w * 8 + t2) * 2048;
        acc[0] = __builtin_amdgcn_mfma_f32_16x16x32_bf16(af, *(const short8*)(tb + 0 * 512), acc[0], 0, 0, 0);
        acc[1] = __builtin_amdgcn_mfma_f32_16x16x32_bf16(af, *(const short8*)(tb + 1 * 512), acc[1], 0, 0, 0);
        acc[2] = __builtin_amdgcn_mfma_f32_16x16x32_bf16(af, *(const short8*)(tb + 2 * 512), acc[2], 0, 0, 0);
        acc[3] = __builtin_amdgcn_mfma_f32_16x16x32_bf16(af, *(const short8*)(tb + 3 * 512), acc[3], 0, 0, 0);
    }
    sum += __shfl_xor(sum, 16, 64);
    sum += __shfl_xor(sum, 32, 64);
    if (quad == 0) ssum[w][rowLane] = sum;
    __syncthreads();  // ssum visible; dsts reads done -> red may overwrite
#pragma unroll
    for (int c = 0; c < 4; ++c)
#pragma unroll
        for (int r = 0; r < 4; ++r)
            red[w][quad * 4 + r][c * 16 + rowLane] = acc[c][r];
    __syncthreads();
    int row = tid >> 4, col4 = (tid & 15) * 4;
    float4 s = make_float4(0.f, 0.f, 0.f, 0.f);
#pragma unroll
    for (int ww = 0; ww < 4; ++ww) {
        float4 v = *(const float4*)&red[ww][row][col4];
        s.x += v.x; s.y += v.y; s.z += v.z; s.w += v.w;
    }
    float invr = 1.0f / (ssum[0][row] + ssum[1][row] + ssum[2][row] + ssum[3][row]);
    s.x *= invr; s.y *= invr; s.z *= invr; s.w *= invr;
    *(float4*)&hp[((size_t)bh * N + n0 + row) * DH + col4] = s;
}

// ---- k_ln: LN(h + concat(hp)); emits swizzled bf16 + next-layer src/dst ----
__global__ __launch_bounds__(256) void k_ln(const float* __restrict__ h,
                                            const float* __restrict__ hp,
                                            const float* __restrict__ scale,
                                            const float* __restrict__ bias,
                                            float* __restrict__ out,
                                            unsigned short* __restrict__ h_sw,
                                            const float* __restrict__ wa_src,
                                            const float* __restrict__ wa_dst,
                                            float* __restrict__ srcv,
                                            float* __restrict__ dstv,
                                            int layer, int has_next) {
    __shared__ float red[8];
    __shared__ float red2[8][4];
    int bn = blockIdx.x;
    int b = bn >> 10, n = bn & 1023;
    int c = threadIdx.x;
    int hh = c >> 6, k = c & 63;
    float x = h[(size_t)bn * D + c] + hp[((size_t)(b * H + hh) * N + n) * DH + k];
    float s = x, s2 = x * x;
#pragma unroll
    for (int off = 32; off; off >>= 1) {
        s += __shfl_xor(s, off, 64);
        s2 += __shfl_xor(s2, off, 64);
    }
    int w = c >> 6, lane = c & 63;
    if (lane == 0) { red[w] = s; red[4 + w] = s2; }
    __syncthreads();
    s = red[0] + red[1] + red[2] + red[3];
    s2 = red[4] + red[5] + red[6] + red[7];
    float mu = s * (1.0f / D);
    float var = s2 * (1.0f / D) - mu * mu;
    float r = rsqrtf(var + 1e-5f);
    float y = (x - mu) * r * scale[layer * D + c] + bias[layer * D + c];
    out[(size_t)bn * D + c] = y;
    if (has_next) {
        h_sw[(((size_t)b * 64 + (n >> 4)) * 8 + (c >> 5)) * 512 + (n & 15) * 32 + (c & 31)] = f2bf(y);
        float sv[4], dv[4];
#pragma unroll
        for (int h2 = 0; h2 < H; ++h2) {
            sv[h2] = y * wa_src[h2 * D + c];
            dv[h2] = y * wa_dst[h2 * D + c];
        }
#pragma unroll
        for (int off = 32; off; off >>= 1) {
#pragma unroll
            for (int h2 = 0; h2 < H; ++h2) {
                sv[h2] += __shfl_xor(sv[h2], off, 64);
                dv[h2] += __shfl_xor(dv[h2], off, 64);
            }
        }
        if (lane < 4) red2[lane][w] = sv[lane];
        else if (lane < 8) red2[lane][w] = dv[lane - 4];
        __syncthreads();
        if (c < 8) {
            float v = red2[c][0] + red2[c][1] + red2[c][2] + red2[c][3];
            int h2 = c & 3;
            if (c < 4) srcv[(b * H + h2) * N + n] = v;
            else dstv[(b * H + h2) * N + n] = v;
        }
    }
}

extern "C" void kernel_launch(void* const* d_in, const int* in_sizes, int n_in,
                              void* d_out, int out_size, void* d_ws, size_t ws_size,
                              hipStream_t stream) {
    const int* cfg_adj = (const int*)d_in[0];
    const int* cfg_nodes = (const int*)d_in[1];
    const int* cfg_len = (const int*)d_in[2];
    const float* emb = (const float*)d_in[3];
    const float* W = (const float*)d_in[4];
    const float* a_src = (const float*)d_in[5];
    const float* a_dst = (const float*)d_in[6];
    const float* ln_scale = (const float*)d_in[7];
    const float* ln_bias = (const float*)d_in[8];
    float* out = (float*)d_out;
    float* ws = (float*)d_ws;

    float* h = ws;
    float* hp = h + (size_t)B * N * D;
    float* srcv = hp + (size_t)B * H * N * DH;
    float* dstv = srcv + (size_t)B * H * N;
    unsigned short* h_sw = (unsigned short*)(dstv + (size_t)B * H * N);
    unsigned short* WhT = h_sw + (size_t)B * N * D;
    unsigned short* WT_sw = WhT + (size_t)B * H * DH * N;
    float* wa_src = (float*)(WT_sw + (size_t)NLAYERS * H * DH * D);
    float* wa_dst = wa_src + NLAYERS * H * D;
    unsigned long long* pack = (unsigned long long*)(wa_dst + NLAYERS * H * D);

    k_pre1<<<2048 + NLAYERS * H * 4 + 1, 256, 0, stream>>>(
        cfg_adj, W, a_src, a_dst, cfg_len, pack, WT_sw, wa_src, wa_dst,
        out + (size_t)B * N * D);
    k_nodefeat<<<B * N / 4, 256, 0, stream>>>(cfg_nodes, emb, wa_src, wa_dst, h, h_sw, srcv, dstv);
    for (int l = 0; l < NLAYERS; ++l) {
        k_wh<<<dim3(B * 64, H), 256, 0, stream>>>(h_sw, WT_sw + (size_t)l * H * 8 * 2048, WhT);
        k_attn<<<B * H * 64, 256, 0, stream>>>(pack, srcv, dstv, WhT, hp);
        k_ln<<<B * N, 256, 0, stream>>>(h, hp, ln_scale, ln_bias,
                                        (l == NLAYERS - 1) ? out : h, h_sw,
                                        wa_src + (size_t)(l + 1) * H * D,
                                        wa_dst + (size_t)(l + 1) * H * D,
                                        srcv, dstv, l, l < NLAYERS - 1 ? 1 : 0);
    }
}

// Round 8
// 226.759 us; speedup vs baseline: 1.7563x; 1.0357x over previous
//
#include <hip/hip_runtime.h>
#include <math.h>

#define B 8
#define N 1024
#define L 16
#define D 256
#define H 4
#define DH 64
#define NLAYERS 2

typedef __attribute__((ext_vector_type(8))) short short8;
typedef __attribute__((ext_vector_type(4))) float f32x4;

__device__ inline unsigned short f2bf(float x) {
    unsigned u = __float_as_uint(x);
    u = (u + 0x7fff + ((u >> 16) & 1)) >> 16;  // RNE
    return (unsigned short)u;
}
// order-preserving float<->uint for atomicMax
__device__ inline unsigned fenc(float x) {
    unsigned b = __float_as_uint(x);
    return (b & 0x80000000u) ? ~b : (b | 0x80000000u);
}
__device__ inline float fdec(unsigned u) {
    return (u & 0x80000000u) ? __uint_as_float(u ^ 0x80000000u) : __uint_as_float(~u);
}

// -------- swizzled layouts --------
// h_sw  [b][n>>4][d>>5][n&15][d&31]    bf16  (A-operand of k_wh)
// WT_sw [lh][d>>5][dh][d&31]           bf16  (B-operand of k_wh)
// WhT_sw[bh][m>>5][dh][m&31]           bf16  (B-operand of k_attn; m = source node)
// pack  [b][n][m/64]                   u64 adjacency bitmask (+self-loop)
// dstmax[l][bh]                        enc-uint, per-(layer,bh) unmasked max dst

// ---- pre1: packadj (2048) + WT transpose (32) + len/dstmax-init (1) ----
__global__ __launch_bounds__(256) void k_pre1(const int* __restrict__ adj,
                                              const float* __restrict__ W,
                                              const int* __restrict__ len,
                                              unsigned long long* __restrict__ pack,
                                              unsigned short* __restrict__ WT_sw,
                                              unsigned* __restrict__ dstmaxbuf,
                                              float* __restrict__ out_len) {
    int bid = blockIdx.x;
    int t = threadIdx.x;
    if (bid < 2048) {
        int row = bid * 4 + (t >> 6);  // bn
        int lane = t & 63;
        int n = row & (N - 1);
        const int* arow = adj + (long)row * N;
        unsigned long long* prow = pack + (size_t)row * 16;
#pragma unroll
        for (int it = 0; it < 16; ++it) {
            int m = lane + it * 64;
            unsigned long long bits = __ballot(arow[m] != 0 || m == n);
            if (lane == 0) prow[it] = bits;
        }
    } else if (bid < 2048 + NLAYERS * H * 4) {
        int idx = bid - 2048;
        int lh = idx >> 2, q = idx & 3;
        const float* Wl = W + (size_t)lh * D * DH;
        int dh = t & 63;
        int d0 = q * 64 + (t >> 6) * 16;
#pragma unroll
        for (int i = 0; i < 16; ++i) {
            int d = d0 + i;
            WT_sw[(((size_t)lh * 8 + (d >> 5)) * 64 + dh) * 32 + (d & 31)] = f2bf(Wl[(size_t)d * DH + dh]);
        }
    } else {
        if (t < B) out_len[t] = (float)len[t];
        if (t < NLAYERS * B * H) dstmaxbuf[t] = 0u;  // floor of enc()
    }
}

// ---- pre2: node_feat (mean emb) -> h fp32 + h_sw bf16 ----
__global__ __launch_bounds__(256) void k_nodefeat(const int* __restrict__ nodes,
                                                  const float* __restrict__ emb,
                                                  float* __restrict__ h,
                                                  unsigned short* __restrict__ h_sw) {
    int bn = blockIdx.x * 4 + (threadIdx.x >> 6);
    int lane = threadIdx.x & 63;
    int d4 = lane * 4;
    const int* np = nodes + bn * L;
    float4 s = make_float4(0.f, 0.f, 0.f, 0.f);
#pragma unroll
    for (int l = 0; l < L; ++l) {
        float4 v = *(const float4*)&emb[(size_t)np[l] * D + d4];
        s.x += v.x; s.y += v.y; s.z += v.z; s.w += v.w;
    }
    s.x *= (1.0f / L); s.y *= (1.0f / L); s.z *= (1.0f / L); s.w *= (1.0f / L);
    *(float4*)&h[(size_t)bn * D + d4] = s;
    int b = bn >> 10, n = bn & 1023;
    ushort4 bv;
    bv.x = f2bf(s.x); bv.y = f2bf(s.y); bv.z = f2bf(s.z); bv.w = f2bf(s.w);
    *(ushort4*)&h_sw[(((size_t)b * 64 + (n >> 4)) * 8 + (d4 >> 5)) * 512 + (n & 15) * 32 + (d4 & 31)] = bv;
}

// ---- k_wh: WhT_sw = (h @ W)^T via MFMA; epilogue computes srcv/dstv = Wh·a
// and per-bh dst max (atomicMax, enc-uint). Block = (b, 16-row tile, head). ----
__global__ __launch_bounds__(256) void k_wh(const unsigned short* __restrict__ h_sw,
                                            const unsigned short* __restrict__ WT_l,
                                            const float* __restrict__ asrc_l,
                                            const float* __restrict__ adst_l,
                                            unsigned short* __restrict__ WhT,
                                            float* __restrict__ srcv,
                                            float* __restrict__ dstv,
                                            unsigned* __restrict__ dstmax_l) {
    __shared__ float red[4][16][68];
    __shared__ float dmx[16];
    int bt = blockIdx.x;   // b*64 + nt
    int hh = blockIdx.y;
    int b = bt >> 6;
    int nt = bt & 63;
    int n0 = nt * 16;
    int tid = threadIdx.x;
    int w = tid >> 6, lane = tid & 63;
    int rowLane = lane & 15, quad = lane >> 4;
    int bh = b * H + hh;
    const unsigned short* abase = h_sw + (((size_t)b * 64 + nt) * 8) * 512 + rowLane * 32 + quad * 8;
    const unsigned short* bbase = WT_l + ((size_t)hh * 8) * 2048 + rowLane * 32 + quad * 8;
    f32x4 acc[4] = {};
#pragma unroll
    for (int kk = 0; kk < 2; ++kk) {
        int kc = w * 2 + kk;
        short8 af = *(const short8*)(abase + kc * 512);
#pragma unroll
        for (int c = 0; c < 4; ++c) {
            short8 bf = *(const short8*)(bbase + kc * 2048 + c * 512);
            acc[c] = __builtin_amdgcn_mfma_f32_16x16x32_bf16(af, bf, acc[c], 0, 0, 0);
        }
    }
#pragma unroll
    for (int c = 0; c < 4; ++c)
#pragma unroll
        for (int r = 0; r < 4; ++r)
            red[w][quad * 4 + r][c * 16 + rowLane] = acc[c][r];
    __syncthreads();
    int dh = tid >> 2, j4 = tid & 3;
    float v[4];
#pragma unroll
    for (int i = 0; i < 4; ++i)
        v[i] = red[0][j4 * 4 + i][dh] + red[1][j4 * 4 + i][dh] + red[2][j4 * 4 + i][dh] + red[3][j4 * 4 + i][dh];
    ushort4 o;
    o.x = f2bf(v[0]); o.y = f2bf(v[1]); o.z = f2bf(v[2]); o.w = f2bf(v[3]);
    *(ushort4*)&WhT[(((size_t)bh * 32 + (n0 >> 5)) * 64 + dh) * 32 + (n0 & 31) + j4 * 4] = o;
    // ---- srcv/dstv = Wh·a (reuse red as ps[16][68] / pd[16][68]) ----
    float as = asrc_l[hh * DH + dh];
    float ad = adst_l[hh * DH + dh];
    float* ps = &red[0][0][0];
    float* pd = ps + 16 * 68;
    __syncthreads();   // red reads done
#pragma unroll
    for (int i = 0; i < 4; ++i) {
        ps[(j4 * 4 + i) * 68 + dh] = v[i] * as;
        pd[(j4 * 4 + i) * 68 + dh] = v[i] * ad;
    }
    __syncthreads();
    int nl = tid >> 4, g = tid & 15;
    float4 s4 = *(float4*)&ps[nl * 68 + g * 4];
    float4 t4 = *(float4*)&pd[nl * 68 + g * 4];
    float s1 = s4.x + s4.y + s4.z + s4.w;
    float d1 = t4.x + t4.y + t4.z + t4.w;
#pragma unroll
    for (int off = 8; off; off >>= 1) {
        s1 += __shfl_xor(s1, off, 16);
        d1 += __shfl_xor(d1, off, 16);
    }
    if (g == 0) {
        srcv[bh * N + n0 + nl] = s1;
        dstv[bh * N + n0 + nl] = d1;
        dmx[nl] = d1;
    }
    __syncthreads();
    if (tid == 0) {
        float m = dmx[0];
#pragma unroll
        for (int i = 1; i < 16; ++i) m = fmaxf(m, dmx[i]);
        atomicMax(dstmax_l + bh, fenc(m));
    }
}

// ---- k_attn: alpha@Wh with deferred normalization; mx from per-bh dst max.
// Block = (bh, 16-row n-tile). Wave w owns m-slab [w*256,(w+1)*256). ----
__global__ __launch_bounds__(256) void k_attn(const unsigned long long* __restrict__ pack,
                                              const float* __restrict__ srcv,
                                              const float* __restrict__ dstv,
                                              const unsigned* __restrict__ dstmax_l,
                                              const unsigned short* __restrict__ WhT,
                                              float* __restrict__ hp) {
    __shared__ float red[4][16][68];     // first 1024 floats alias dsts[4][256]
    __shared__ float ssum[4][16];
    float* dsts = &red[0][0][0];

    int tid = threadIdx.x;
    int bt = blockIdx.x;
    int bh = bt >> 6;
    int n0 = (bt & 63) * 16;
    int b = bh >> 2;
    int w = tid >> 6, lane = tid & 63;
    int rowLane = lane & 15, quad = lane >> 4;
    int n = n0 + rowLane;

    // stage own wave's dst slab (wave-local; in-wave lgkmcnt suffices)
    {
        float4 v = *(const float4*)(dstv + bh * N + w * 256 + lane * 4);
        *(float4*)(dsts + w * 256 + lane * 4) = v;
    }
    const uint4* pbp = (const uint4*)((const unsigned char*)(pack + ((size_t)(b * N + n)) * 16) + w * 32);
    uint4 pbv0 = pbp[0];
    uint4 pbv1 = pbp[1];
    float src = srcv[bh * N + n];
    float maxd = fdec(dstmax_l[bh]);
    float e0 = src + maxd;
    float mx = e0 > 0.f ? e0 : 0.2f * e0;   // upper bound on all masked e (lrelu monotone)

    // fused pass: build unnormalized alpha A-frags, accumulate S, MFMA
    unsigned words[8] = {pbv0.x, pbv0.y, pbv0.z, pbv0.w, pbv1.x, pbv1.y, pbv1.z, pbv1.w};
    const unsigned short* wbase = WhT + ((size_t)bh * 32) * 2048 + rowLane * 32 + quad * 8;
    f32x4 acc[4] = {};
    float sum = 0.f;
#pragma unroll
    for (int t2 = 0; t2 < 8; ++t2) {
        unsigned bits = (words[t2] >> (quad * 8)) & 0xffu;
        float4 d0 = *(const float4*)(dsts + w * 256 + t2 * 32 + quad * 8);
        float4 d1 = *(const float4*)(dsts + w * 256 + t2 * 32 + quad * 8 + 4);
        float dd[8] = {d0.x, d0.y, d0.z, d0.w, d1.x, d1.y, d1.z, d1.w};
        short8 af;
#pragma unroll
        for (int j = 0; j < 8; ++j) {
            float e = src + dd[j];
            e = e > 0.f ? e : 0.2f * e;
            float p = ((bits >> j) & 1) ? __expf(e - mx) : 0.f;
            sum += p;
            af[j] = (short)f2bf(p);
        }
        const unsigned short* tb = wbase + (size_t)(w * 8 + t2) * 2048;
        acc[0] = __builtin_amdgcn_mfma_f32_16x16x32_bf16(af, *(const short8*)(tb + 0 * 512), acc[0], 0, 0, 0);
        acc[1] = __builtin_amdgcn_mfma_f32_16x16x32_bf16(af, *(const short8*)(tb + 1 * 512), acc[1], 0, 0, 0);
        acc[2] = __builtin_amdgcn_mfma_f32_16x16x32_bf16(af, *(const short8*)(tb + 2 * 512), acc[2], 0, 0, 0);
        acc[3] = __builtin_amdgcn_mfma_f32_16x16x32_bf16(af, *(const short8*)(tb + 3 * 512), acc[3], 0, 0, 0);
    }
    sum += __shfl_xor(sum, 16, 64);
    sum += __shfl_xor(sum, 32, 64);
    if (quad == 0) ssum[w][rowLane] = sum;
    __syncthreads();  // ssum visible; dsts reads done -> red may overwrite
#pragma unroll
    for (int c = 0; c < 4; ++c)
#pragma unroll
        for (int r = 0; r < 4; ++r)
            red[w][quad * 4 + r][c * 16 + rowLane] = acc[c][r];
    __syncthreads();
    int row = tid >> 4, col4 = (tid & 15) * 4;
    float4 s = make_float4(0.f, 0.f, 0.f, 0.f);
#pragma unroll
    for (int ww = 0; ww < 4; ++ww) {
        float4 v = *(const float4*)&red[ww][row][col4];
        s.x += v.x; s.y += v.y; s.z += v.z; s.w += v.w;
    }
    float invr = 1.0f / (ssum[0][row] + ssum[1][row] + ssum[2][row] + ssum[3][row]);
    s.x *= invr; s.y *= invr; s.z *= invr; s.w *= invr;
    *(float4*)&hp[((size_t)bh * N + n0 + row) * DH + col4] = s;
}

// ---- k_ln: LN(h + concat(hp)); emits swizzled bf16 for next layer ----
__global__ __launch_bounds__(256) void k_ln(const float* __restrict__ h,
                                            const float* __restrict__ hp,
                                            const float* __restrict__ scale,
                                            const float* __restrict__ bias,
                                            float* __restrict__ out,
                                            unsigned short* __restrict__ h_sw,
                                            int layer, int has_next) {
    __shared__ float red[8];
    int bn = blockIdx.x;
    int b = bn >> 10, n = bn & 1023;
    int c = threadIdx.x;
    int hh = c >> 6, k = c & 63;
    float x = h[(size_t)bn * D + c] + hp[((size_t)(b * H + hh) * N + n) * DH + k];
    float s = x, s2 = x * x;
#pragma unroll
    for (int off = 32; off; off >>= 1) {
        s += __shfl_xor(s, off, 64);
        s2 += __shfl_xor(s2, off, 64);
    }
    int w = c >> 6, lane = c & 63;
    if (lane == 0) { red[w] = s; red[4 + w] = s2; }
    __syncthreads();
    s = red[0] + red[1] + red[2] + red[3];
    s2 = red[4] + red[5] + red[6] + red[7];
    float mu = s * (1.0f / D);
    float var = s2 * (1.0f / D) - mu * mu;
    float r = rsqrtf(var + 1e-5f);
    float y = (x - mu) * r * scale[layer * D + c] + bias[layer * D + c];
    out[(size_t)bn * D + c] = y;
    if (has_next)
        h_sw[(((size_t)b * 64 + (n >> 4)) * 8 + (c >> 5)) * 512 + (n & 15) * 32 + (c & 31)] = f2bf(y);
}

extern "C" void kernel_launch(void* const* d_in, const int* in_sizes, int n_in,
                              void* d_out, int out_size, void* d_ws, size_t ws_size,
                              hipStream_t stream) {
    const int* cfg_adj = (const int*)d_in[0];
    const int* cfg_nodes = (const int*)d_in[1];
    const int* cfg_len = (const int*)d_in[2];
    const float* emb = (const float*)d_in[3];
    const float* W = (const float*)d_in[4];
    const float* a_src = (const float*)d_in[5];
    const float* a_dst = (const float*)d_in[6];
    const float* ln_scale = (const float*)d_in[7];
    const float* ln_bias = (const float*)d_in[8];
    float* out = (float*)d_out;
    float* ws = (float*)d_ws;

    float* h = ws;
    float* hp = h + (size_t)B * N * D;
    float* srcv = hp + (size_t)B * H * N * DH;
    float* dstv = srcv + (size_t)B * H * N;
    unsigned short* h_sw = (unsigned short*)(dstv + (size_t)B * H * N);
    unsigned short* WhT = h_sw + (size_t)B * N * D;
    unsigned short* WT_sw = WhT + (size_t)B * H * DH * N;
    unsigned long long* pack = (unsigned long long*)(WT_sw + (size_t)NLAYERS * H * DH * D);
    unsigned* dstmaxbuf = (unsigned*)(pack + (size_t)B * N * 16);

    k_pre1<<<2048 + NLAYERS * H * 4 + 1, 256, 0, stream>>>(
        cfg_adj, W, cfg_len, pack, WT_sw, dstmaxbuf, out + (size_t)B * N * D);
    k_nodefeat<<<B * N / 4, 256, 0, stream>>>(cfg_nodes, emb, h, h_sw);
    for (int l = 0; l < NLAYERS; ++l) {
        k_wh<<<dim3(B * 64, H), 256, 0, stream>>>(
            h_sw, WT_sw + (size_t)l * H * 8 * 2048,
            a_src + (size_t)l * H * DH, a_dst + (size_t)l * H * DH,
            WhT, srcv, dstv, dstmaxbuf + (size_t)l * B * H);
        k_attn<<<B * H * 64, 256, 0, stream>>>(pack, srcv, dstv,
                                               dstmaxbuf + (size_t)l * B * H, WhT, hp);
        k_ln<<<B * N, 256, 0, stream>>>(h, hp, ln_scale, ln_bias,
                                        (l == NLAYERS - 1) ? out : h, h_sw,
                                        l, l < NLAYERS - 1 ? 1 : 0);
    }
}

// Round 9
// 223.048 us; speedup vs baseline: 1.7855x; 1.0166x over previous
//
#include <hip/hip_runtime.h>
#include <math.h>

#define B 8
#define N 1024
#define L 16
#define D 256
#define H 4
#define DH 64
#define NLAYERS 2
#define V 32000

typedef __attribute__((ext_vector_type(8))) short short8;
typedef __attribute__((ext_vector_type(4))) float f32x4;

union U8 { uint4 u; short8 s; };

__device__ inline unsigned short f2bf(float x) {
    unsigned u = __float_as_uint(x);
    u = (u + 0x7fff + ((u >> 16) & 1)) >> 16;  // RNE
    return (unsigned short)u;
}
__device__ inline float bf2f(unsigned short x) {
    return __uint_as_float(((unsigned)x) << 16);
}

// -------- swizzled layouts --------
// h_sw  [b][n>>4][d>>5][n&15][d&31]    bf16  (A-operand of k_wh)
// WT_sw [lh][d>>5][dh][d&31]           bf16  (B-operand of k_wh)
// WhT_sw[bh][m>>5][dh][m&31]           bf16  (B-operand of k_attn; m = source node)
// pack  [b][n][m/64]                   u64 adjacency bitmask (+self-loop)
// emb_bf[V][D]                         bf16 copy of emb

#define PACK_BLK 2048
#define WT_BLK   (NLAYERS * H * 4)   // 32
#define EMB_BLK  500                 // V*D/16384 exactly
#define PRE1_GRID (PACK_BLK + WT_BLK + EMB_BLK + 1)

// ---- pre1: packadj + WT transpose + emb->bf16 + len ----
__global__ __launch_bounds__(256) void k_pre1(const int* __restrict__ adj,
                                              const float* __restrict__ W,
                                              const int* __restrict__ len,
                                              const float* __restrict__ emb,
                                              unsigned long long* __restrict__ pack,
                                              unsigned short* __restrict__ WT_sw,
                                              unsigned short* __restrict__ emb_bf,
                                              float* __restrict__ out_len) {
    int bid = blockIdx.x;
    int t = threadIdx.x;
    if (bid < PACK_BLK) {
        int row = bid * 4 + (t >> 6);  // bn
        int lane = t & 63;
        int n = row & (N - 1);
        const int* arow = adj + (long)row * N;
        unsigned long long* prow = pack + (size_t)row * 16;
#pragma unroll
        for (int it = 0; it < 16; ++it) {
            int m = lane + it * 64;
            unsigned long long bits = __ballot(arow[m] != 0 || m == n);
            if (lane == 0) prow[it] = bits;
        }
    } else if (bid < PACK_BLK + WT_BLK) {
        int idx = bid - PACK_BLK;
        int lh = idx >> 2, q = idx & 3;
        const float* Wl = W + (size_t)lh * D * DH;
        int dh = t & 63;
        int d0 = q * 64 + (t >> 6) * 16;
#pragma unroll
        for (int i = 0; i < 16; ++i) {
            int d = d0 + i;
            WT_sw[(((size_t)lh * 8 + (d >> 5)) * 64 + dh) * 32 + (d & 31)] = f2bf(Wl[(size_t)d * DH + dh]);
        }
    } else if (bid < PACK_BLK + WT_BLK + EMB_BLK) {
        size_t base = (size_t)(bid - PACK_BLK - WT_BLK) * 16384 + (size_t)t * 64;
#pragma unroll
        for (int i = 0; i < 16; ++i) {
            float4 v = *(const float4*)&emb[base + i * 4];
            ushort4 o;
            o.x = f2bf(v.x); o.y = f2bf(v.y); o.z = f2bf(v.z); o.w = f2bf(v.w);
            *(ushort4*)&emb_bf[base + i * 4] = o;
        }
    } else {
        if (t < B) out_len[t] = (float)len[t];
    }
}

// ---- nodefeat: mean of bf16 token embeddings -> h fp32 + h_sw bf16 ----
// 8 rows/block; 32 lanes per row, each lane covers 8 consecutive d.
__global__ __launch_bounds__(256) void k_nodefeat(const int* __restrict__ nodes,
                                                  const unsigned short* __restrict__ emb_bf,
                                                  float* __restrict__ h,
                                                  unsigned short* __restrict__ h_sw) {
    int row = blockIdx.x * 8 + (threadIdx.x >> 5);  // bn
    int lane32 = threadIdx.x & 31;
    int d8 = lane32 * 8;
    const int* np = nodes + row * L;
    float s[8] = {};
#pragma unroll
    for (int l = 0; l < L; ++l) {
        short8 v = *(const short8*)&emb_bf[(size_t)np[l] * D + d8];
#pragma unroll
        for (int k = 0; k < 8; ++k) s[k] += bf2f((unsigned short)v[k]);
    }
#pragma unroll
    for (int k = 0; k < 8; ++k) s[k] *= (1.0f / L);
    *(float4*)&h[(size_t)row * D + d8] = make_float4(s[0], s[1], s[2], s[3]);
    *(float4*)&h[(size_t)row * D + d8 + 4] = make_float4(s[4], s[5], s[6], s[7]);
    int b = row >> 10, n = row & 1023;
    unsigned short o[8];
#pragma unroll
    for (int k = 0; k < 8; ++k) o[k] = f2bf(s[k]);
    *(short8*)&h_sw[(((size_t)b * 64 + (n >> 4)) * 8 + (d8 >> 5)) * 512 + (n & 15) * 32 + (d8 & 31)] =
        *(short8*)o;
}

// ---- k_wh: WhT_sw = (h @ W)^T via MFMA; epilogue computes srcv/dstv = Wh·a ----
__global__ __launch_bounds__(256) void k_wh(const unsigned short* __restrict__ h_sw,
                                            const unsigned short* __restrict__ WT_l,
                                            const float* __restrict__ asrc_l,
                                            const float* __restrict__ adst_l,
                                            unsigned short* __restrict__ WhT,
                                            float* __restrict__ srcv,
                                            float* __restrict__ dstv) {
    __shared__ float red[4][16][68];
    int bt = blockIdx.x;   // b*64 + nt
    int hh = blockIdx.y;
    int b = bt >> 6;
    int nt = bt & 63;
    int n0 = nt * 16;
    int tid = threadIdx.x;
    int w = tid >> 6, lane = tid & 63;
    int rowLane = lane & 15, quad = lane >> 4;
    int bh = b * H + hh;
    const unsigned short* abase = h_sw + (((size_t)b * 64 + nt) * 8) * 512 + rowLane * 32 + quad * 8;
    const unsigned short* bbase = WT_l + ((size_t)hh * 8) * 2048 + rowLane * 32 + quad * 8;
    f32x4 acc[4] = {};
#pragma unroll
    for (int kk = 0; kk < 2; ++kk) {
        int kc = w * 2 + kk;
        short8 af = *(const short8*)(abase + kc * 512);
#pragma unroll
        for (int c = 0; c < 4; ++c) {
            short8 bf = *(const short8*)(bbase + kc * 2048 + c * 512);
            acc[c] = __builtin_amdgcn_mfma_f32_16x16x32_bf16(af, bf, acc[c], 0, 0, 0);
        }
    }
#pragma unroll
    for (int c = 0; c < 4; ++c)
#pragma unroll
        for (int r = 0; r < 4; ++r)
            red[w][quad * 4 + r][c * 16 + rowLane] = acc[c][r];
    __syncthreads();
    int dh = tid >> 2, j4 = tid & 3;
    float v[4];
#pragma unroll
    for (int i = 0; i < 4; ++i)
        v[i] = red[0][j4 * 4 + i][dh] + red[1][j4 * 4 + i][dh] + red[2][j4 * 4 + i][dh] + red[3][j4 * 4 + i][dh];
    ushort4 o;
    o.x = f2bf(v[0]); o.y = f2bf(v[1]); o.z = f2bf(v[2]); o.w = f2bf(v[3]);
    *(ushort4*)&WhT[(((size_t)bh * 32 + (n0 >> 5)) * 64 + dh) * 32 + (n0 & 31) + j4 * 4] = o;
    // ---- srcv/dstv = Wh·a (reuse red as ps[16][68] / pd[16][68]) ----
    float as = asrc_l[hh * DH + dh];
    float ad = adst_l[hh * DH + dh];
    float* ps = &red[0][0][0];
    float* pd = ps + 16 * 68;
    __syncthreads();   // red reads done
#pragma unroll
    for (int i = 0; i < 4; ++i) {
        ps[(j4 * 4 + i) * 68 + dh] = v[i] * as;
        pd[(j4 * 4 + i) * 68 + dh] = v[i] * ad;
    }
    __syncthreads();
    int nl = tid >> 4, g = tid & 15;
    float4 s4 = *(float4*)&ps[nl * 68 + g * 4];
    float4 t4 = *(float4*)&pd[nl * 68 + g * 4];
    float s1 = s4.x + s4.y + s4.z + s4.w;
    float d1 = t4.x + t4.y + t4.z + t4.w;
#pragma unroll
    for (int off = 8; off; off >>= 1) {
        s1 += __shfl_xor(s1, off, 16);
        d1 += __shfl_xor(d1, off, 16);
    }
    if (g == 0) {
        srcv[bh * N + n0 + nl] = s1;
        dstv[bh * N + n0 + nl] = d1;
    }
}

// ---- k_attn: alpha@Wh, deferred normalization, local shift mx=lrelu(src).
// h' is exactly invariant to the shift; it only keeps exp() in fp range.
// Block = (bh, 16-row n-tile). Wave w owns m-slab [w*256,(w+1)*256). ----
__global__ __launch_bounds__(256) void k_attn(const unsigned long long* __restrict__ pack,
                                              const float* __restrict__ srcv,
                                              const float* __restrict__ dstv,
                                              const unsigned short* __restrict__ WhT,
                                              float* __restrict__ hp) {
    __shared__ float red[4][16][68];     // first 1024 floats alias dsts[4][256]
    __shared__ float ssum[4][16];
    float* dsts = &red[0][0][0];

    int tid = threadIdx.x;
    int bt = blockIdx.x;
    int bh = bt >> 6;
    int n0 = (bt & 63) * 16;
    int b = bh >> 2;
    int w = tid >> 6, lane = tid & 63;
    int rowLane = lane & 15, quad = lane >> 4;
    int n = n0 + rowLane;

    // stage own wave's dst slab (wave-local; in-wave lgkmcnt ordering suffices)
    {
        float4 v = *(const float4*)(dstv + bh * N + w * 256 + lane * 4);
        *(float4*)(dsts + w * 256 + lane * 4) = v;
    }
    const uint4* pbp = (const uint4*)((const unsigned char*)(pack + ((size_t)(b * N + n)) * 16) + w * 32);
    uint4 pbv0 = pbp[0];
    uint4 pbv1 = pbp[1];
    float src = srcv[bh * N + n];
    float mx = src > 0.f ? src : 0.2f * src;   // local stable shift

    unsigned words[8] = {pbv0.x, pbv0.y, pbv0.z, pbv0.w, pbv1.x, pbv1.y, pbv1.z, pbv1.w};
    const unsigned short* wbase = WhT + ((size_t)bh * 32) * 2048 + rowLane * 32 + quad * 8;
    f32x4 acc[4] = {};
    float sum0 = 0.f, sum1 = 0.f;
#pragma unroll
    for (int t2 = 0; t2 < 8; ++t2) {
        unsigned bits = (words[t2] >> (quad * 8)) & 0xffu;
        float4 d0 = *(const float4*)(dsts + w * 256 + t2 * 32 + quad * 8);
        float4 d1 = *(const float4*)(dsts + w * 256 + t2 * 32 + quad * 8 + 4);
        float dd[8] = {d0.x, d0.y, d0.z, d0.w, d1.x, d1.y, d1.z, d1.w};
        unsigned pk[4];
#pragma unroll
        for (int j2 = 0; j2 < 4; ++j2) {
            float ea = src + dd[2 * j2];
            float eb = src + dd[2 * j2 + 1];
            ea = ea > 0.f ? ea : 0.2f * ea;
            eb = eb > 0.f ? eb : 0.2f * eb;
            float pa = ((bits >> (2 * j2)) & 1) ? __expf(ea - mx) : 0.f;
            float pb = ((bits >> (2 * j2 + 1)) & 1) ? __expf(eb - mx) : 0.f;
            sum0 += pa; sum1 += pb;
            // truncating bf16 pack (p >= 0; normalization absorbs <=0.4% bias)
            pk[j2] = (__float_as_uint(pb) & 0xffff0000u) | (__float_as_uint(pa) >> 16);
        }
        U8 u; u.u = make_uint4(pk[0], pk[1], pk[2], pk[3]);
        short8 af = u.s;
        const unsigned short* tb = wbase + (size_t)(w * 8 + t2) * 2048;
        acc[0] = __builtin_amdgcn_mfma_f32_16x16x32_bf16(af, *(const short8*)(tb + 0 * 512), acc[0], 0, 0, 0);
        acc[1] = __builtin_amdgcn_mfma_f32_16x16x32_bf16(af, *(const short8*)(tb + 1 * 512), acc[1], 0, 0, 0);
        acc[2] = __builtin_amdgcn_mfma_f32_16x16x32_bf16(af, *(const short8*)(tb + 2 * 512), acc[2], 0, 0, 0);
        acc[3] = __builtin_amdgcn_mfma_f32_16x16x32_bf16(af, *(const short8*)(tb + 3 * 512), acc[3], 0, 0, 0);
    }
    float sum = sum0 + sum1;
    sum += __shfl_xor(sum, 16, 64);
    sum += __shfl_xor(sum, 32, 64);
    if (quad == 0) ssum[w][rowLane] = sum;
    __syncthreads();  // ssum visible; dsts reads done -> red may overwrite
#pragma unroll
    for (int c = 0; c < 4; ++c)
#pragma unroll
        for (int r = 0; r < 4; ++r)
            red[w][quad * 4 + r][c * 16 + rowLane] = acc[c][r];
    __syncthreads();
    int row = tid >> 4, col4 = (tid & 15) * 4;
    float4 s = make_float4(0.f, 0.f, 0.f, 0.f);
#pragma unroll
    for (int ww = 0; ww < 4; ++ww) {
        float4 v = *(const float4*)&red[ww][row][col4];
        s.x += v.x; s.y += v.y; s.z += v.z; s.w += v.w;
    }
    float invr = 1.0f / (ssum[0][row] + ssum[1][row] + ssum[2][row] + ssum[3][row]);
    s.x *= invr; s.y *= invr; s.z *= invr; s.w *= invr;
    *(float4*)&hp[((size_t)bh * N + n0 + row) * DH + col4] = s;
}

// ---- k_ln: LN(h + concat(hp)); emits swizzled bf16 for next layer ----
__global__ __launch_bounds__(256) void k_ln(const float* __restrict__ h,
                                            const float* __restrict__ hp,
                                            const float* __restrict__ scale,
                                            const float* __restrict__ bias,
                                            float* __restrict__ out,
                                            unsigned short* __restrict__ h_sw,
                                            int layer, int has_next) {
    __shared__ float red[8];
    int bn = blockIdx.x;
    int b = bn >> 10, n = bn & 1023;
    int c = threadIdx.x;
    int hh = c >> 6, k = c & 63;
    float x = h[(size_t)bn * D + c] + hp[((size_t)(b * H + hh) * N + n) * DH + k];
    float s = x, s2 = x * x;
#pragma unroll
    for (int off = 32; off; off >>= 1) {
        s += __shfl_xor(s, off, 64);
        s2 += __shfl_xor(s2, off, 64);
    }
    int w = c >> 6, lane = c & 63;
    if (lane == 0) { red[w] = s; red[4 + w] = s2; }
    __syncthreads();
    s = red[0] + red[1] + red[2] + red[3];
    s2 = red[4] + red[5] + red[6] + red[7];
    float mu = s * (1.0f / D);
    float var = s2 * (1.0f / D) - mu * mu;
    float r = rsqrtf(var + 1e-5f);
    float y = (x - mu) * r * scale[layer * D + c] + bias[layer * D + c];
    out[(size_t)bn * D + c] = y;
    if (has_next)
        h_sw[(((size_t)b * 64 + (n >> 4)) * 8 + (c >> 5)) * 512 + (n & 15) * 32 + (c & 31)] = f2bf(y);
}

extern "C" void kernel_launch(void* const* d_in, const int* in_sizes, int n_in,
                              void* d_out, int out_size, void* d_ws, size_t ws_size,
                              hipStream_t stream) {
    const int* cfg_adj = (const int*)d_in[0];
    const int* cfg_nodes = (const int*)d_in[1];
    const int* cfg_len = (const int*)d_in[2];
    const float* emb = (const float*)d_in[3];
    const float* W = (const float*)d_in[4];
    const float* a_src = (const float*)d_in[5];
    const float* a_dst = (const float*)d_in[6];
    const float* ln_scale = (const float*)d_in[7];
    const float* ln_bias = (const float*)d_in[8];
    float* out = (float*)d_out;
    float* ws = (float*)d_ws;

    float* h = ws;
    float* hp = h + (size_t)B * N * D;
    float* srcv = hp + (size_t)B * H * N * DH;
    float* dstv = srcv + (size_t)B * H * N;
    unsigned short* h_sw = (unsigned short*)(dstv + (size_t)B * H * N);
    unsigned short* WhT = h_sw + (size_t)B * N * D;
    unsigned short* WT_sw = WhT + (size_t)B * H * DH * N;
    unsigned short* emb_bf = WT_sw + (size_t)NLAYERS * H * DH * D;
    unsigned long long* pack = (unsigned long long*)(emb_bf + (size_t)V * D);

    k_pre1<<<PRE1_GRID, 256, 0, stream>>>(cfg_adj, W, cfg_len, emb, pack, WT_sw,
                                          emb_bf, out + (size_t)B * N * D);
    k_nodefeat<<<B * N / 8, 256, 0, stream>>>(cfg_nodes, emb_bf, h, h_sw);
    for (int l = 0; l < NLAYERS; ++l) {
        k_wh<<<dim3(B * 64, H), 256, 0, stream>>>(
            h_sw, WT_sw + (size_t)l * H * 8 * 2048,
            a_src + (size_t)l * H * DH, a_dst + (size_t)l * H * DH,
            WhT, srcv, dstv);
        k_attn<<<B * H * 64, 256, 0, stream>>>(pack, srcv, dstv, WhT, hp);
        k_ln<<<B * N, 256, 0, stream>>>(h, hp, ln_scale, ln_bias,
                                        (l == NLAYERS - 1) ? out : h, h_sw,
                                        l, l < NLAYERS - 1 ? 1 : 0);
    }
}

// Round 10
// 203.727 us; speedup vs baseline: 1.9548x; 1.0948x over previous
//
#include <hip/hip_runtime.h>
#include <math.h>

#define B 8
#define N 1024
#define L 16
#define D 256
#define H 4
#define DH 64
#define NLAYERS 2
#define V 32000

typedef __attribute__((ext_vector_type(8))) short short8;
typedef __attribute__((ext_vector_type(4))) float f32x4;

union U8 { uint4 u; short8 s; };

__device__ inline unsigned short f2bf(float x) {
    unsigned u = __float_as_uint(x);
    u = (u + 0x7fff + ((u >> 16) & 1)) >> 16;  // RNE
    return (unsigned short)u;
}
__device__ inline float bf2f(unsigned short x) {
    return __uint_as_float(((unsigned)x) << 16);
}

// -------- swizzled layouts --------
// h_sw  [b][n>>4][d>>5][n&15][d&31]    bf16  (A-operand of k_wh)
// WT_sw [lh][d>>5][dh][d&31]           bf16  (B-operand of k_wh)
// WhT_sw[bh][m>>5][dh][m&31]           bf16  (B-operand of k_attn; m = source node)
// pack  [b][n][m/64]                   u64 adjacency bitmask (+self-loop)
// emb_bf[V][D]                         bf16 copy of emb

#define PACK_BLK 2048
#define WT_BLK   (NLAYERS * H * 4)   // 32
#define EMB_BLK  500                 // V*D/16384 exactly
#define PRE1_GRID (PACK_BLK + WT_BLK + EMB_BLK + 1)

// ---- pre1: packadj (int4 + nibble-shuffle) + WT transpose + emb->bf16 + len ----
__global__ __launch_bounds__(256) void k_pre1(const int* __restrict__ adj,
                                              const float* __restrict__ W,
                                              const int* __restrict__ len,
                                              const float* __restrict__ emb,
                                              unsigned long long* __restrict__ pack,
                                              unsigned short* __restrict__ WT_sw,
                                              unsigned short* __restrict__ emb_bf,
                                              float* __restrict__ out_len) {
    int bid = blockIdx.x;
    int t = threadIdx.x;
    if (bid < PACK_BLK) {
        int row = bid * 4 + (t >> 6);  // bn
        int lane = t & 63;
        int n = row & (N - 1);
        const int* arow = adj + (long)row * N;
        unsigned long long* prow = pack + (size_t)row * 16;
        int g16 = lane & 15;
#pragma unroll
        for (int it = 0; it < 4; ++it) {
            int m0 = it * 256 + lane * 4;
            int4 a = *(const int4*)(arow + m0);
            unsigned nib = (unsigned)((a.x != 0) || (m0 == n))
                         | ((unsigned)((a.y != 0) || (m0 + 1 == n)) << 1)
                         | ((unsigned)((a.z != 0) || (m0 + 2 == n)) << 2)
                         | ((unsigned)((a.w != 0) || (m0 + 3 == n)) << 3);
            unsigned long long v = (unsigned long long)nib << (g16 * 4);
            // OR-reduce within each 16-lane group (offsets 1/2/4/8 stay in-group)
            v |= __shfl_xor(v, 1, 64);
            v |= __shfl_xor(v, 2, 64);
            v |= __shfl_xor(v, 4, 64);
            v |= __shfl_xor(v, 8, 64);
            if (g16 == 0) prow[it * 4 + (lane >> 4)] = v;
        }
    } else if (bid < PACK_BLK + WT_BLK) {
        int idx = bid - PACK_BLK;
        int lh = idx >> 2, q = idx & 3;
        const float* Wl = W + (size_t)lh * D * DH;
        int dh = t & 63;
        int d0 = q * 64 + (t >> 6) * 16;
#pragma unroll
        for (int i = 0; i < 16; ++i) {
            int d = d0 + i;
            WT_sw[(((size_t)lh * 8 + (d >> 5)) * 64 + dh) * 32 + (d & 31)] = f2bf(Wl[(size_t)d * DH + dh]);
        }
    } else if (bid < PACK_BLK + WT_BLK + EMB_BLK) {
        // coalesced: iteration i covers 1024 consecutive floats, lane t gets 4
        size_t base = (size_t)(bid - PACK_BLK - WT_BLK) * 16384 + (size_t)t * 4;
#pragma unroll
        for (int i = 0; i < 16; ++i) {
            float4 v = *(const float4*)&emb[base + (size_t)i * 1024];
            ushort4 o;
            o.x = f2bf(v.x); o.y = f2bf(v.y); o.z = f2bf(v.z); o.w = f2bf(v.w);
            *(ushort4*)&emb_bf[base + (size_t)i * 1024] = o;
        }
    } else {
        if (t < B) out_len[t] = (float)len[t];
    }
}

// ---- nodefeat: mean of bf16 token embeddings -> h fp32 + h_sw bf16 ----
// 8 rows/block; 32 lanes per row, each lane covers 8 consecutive d.
__global__ __launch_bounds__(256) void k_nodefeat(const int* __restrict__ nodes,
                                                  const unsigned short* __restrict__ emb_bf,
                                                  float* __restrict__ h,
                                                  unsigned short* __restrict__ h_sw) {
    int row = blockIdx.x * 8 + (threadIdx.x >> 5);  // bn
    int lane32 = threadIdx.x & 31;
    int d8 = lane32 * 8;
    const int* np = nodes + row * L;
    float s[8] = {};
#pragma unroll
    for (int l = 0; l < L; ++l) {
        short8 v = *(const short8*)&emb_bf[(size_t)np[l] * D + d8];
#pragma unroll
        for (int k = 0; k < 8; ++k) s[k] += bf2f((unsigned short)v[k]);
    }
#pragma unroll
    for (int k = 0; k < 8; ++k) s[k] *= (1.0f / L);
    *(float4*)&h[(size_t)row * D + d8] = make_float4(s[0], s[1], s[2], s[3]);
    *(float4*)&h[(size_t)row * D + d8 + 4] = make_float4(s[4], s[5], s[6], s[7]);
    int b = row >> 10, n = row & 1023;
    unsigned short o[8];
#pragma unroll
    for (int k = 0; k < 8; ++k) o[k] = f2bf(s[k]);
    *(short8*)&h_sw[(((size_t)b * 64 + (n >> 4)) * 8 + (d8 >> 5)) * 512 + (n & 15) * 32 + (d8 & 31)] =
        *(short8*)o;
}

// ---- k_wh: WhT_sw = (h @ W)^T via MFMA; epilogue computes srcv/dstv = Wh·a ----
__global__ __launch_bounds__(256) void k_wh(const unsigned short* __restrict__ h_sw,
                                            const unsigned short* __restrict__ WT_l,
                                            const float* __restrict__ asrc_l,
                                            const float* __restrict__ adst_l,
                                            unsigned short* __restrict__ WhT,
                                            float* __restrict__ srcv,
                                            float* __restrict__ dstv) {
    __shared__ float red[4][16][68];
    int bt = blockIdx.x;   // b*64 + nt
    int hh = blockIdx.y;
    int b = bt >> 6;
    int nt = bt & 63;
    int n0 = nt * 16;
    int tid = threadIdx.x;
    int w = tid >> 6, lane = tid & 63;
    int rowLane = lane & 15, quad = lane >> 4;
    int bh = b * H + hh;
    const unsigned short* abase = h_sw + (((size_t)b * 64 + nt) * 8) * 512 + rowLane * 32 + quad * 8;
    const unsigned short* bbase = WT_l + ((size_t)hh * 8) * 2048 + rowLane * 32 + quad * 8;
    f32x4 acc[4] = {};
#pragma unroll
    for (int kk = 0; kk < 2; ++kk) {
        int kc = w * 2 + kk;
        short8 af = *(const short8*)(abase + kc * 512);
#pragma unroll
        for (int c = 0; c < 4; ++c) {
            short8 bf = *(const short8*)(bbase + kc * 2048 + c * 512);
            acc[c] = __builtin_amdgcn_mfma_f32_16x16x32_bf16(af, bf, acc[c], 0, 0, 0);
        }
    }
#pragma unroll
    for (int c = 0; c < 4; ++c)
#pragma unroll
        for (int r = 0; r < 4; ++r)
            red[w][quad * 4 + r][c * 16 + rowLane] = acc[c][r];
    __syncthreads();
    int dh = tid >> 2, j4 = tid & 3;
    float v[4];
#pragma unroll
    for (int i = 0; i < 4; ++i)
        v[i] = red[0][j4 * 4 + i][dh] + red[1][j4 * 4 + i][dh] + red[2][j4 * 4 + i][dh] + red[3][j4 * 4 + i][dh];
    ushort4 o;
    o.x = f2bf(v[0]); o.y = f2bf(v[1]); o.z = f2bf(v[2]); o.w = f2bf(v[3]);
    *(ushort4*)&WhT[(((size_t)bh * 32 + (n0 >> 5)) * 64 + dh) * 32 + (n0 & 31) + j4 * 4] = o;
    // ---- srcv/dstv = Wh·a (reuse red as ps[16][68] / pd[16][68]) ----
    float as = asrc_l[hh * DH + dh];
    float ad = adst_l[hh * DH + dh];
    float* ps = &red[0][0][0];
    float* pd = ps + 16 * 68;
    __syncthreads();   // red reads done
#pragma unroll
    for (int i = 0; i < 4; ++i) {
        ps[(j4 * 4 + i) * 68 + dh] = v[i] * as;
        pd[(j4 * 4 + i) * 68 + dh] = v[i] * ad;
    }
    __syncthreads();
    int nl = tid >> 4, g = tid & 15;
    float4 s4 = *(float4*)&ps[nl * 68 + g * 4];
    float4 t4 = *(float4*)&pd[nl * 68 + g * 4];
    float s1 = s4.x + s4.y + s4.z + s4.w;
    float d1 = t4.x + t4.y + t4.z + t4.w;
#pragma unroll
    for (int off = 8; off; off >>= 1) {
        s1 += __shfl_xor(s1, off, 16);
        d1 += __shfl_xor(d1, off, 16);
    }
    if (g == 0) {
        srcv[bh * N + n0 + nl] = s1;
        dstv[bh * N + n0 + nl] = d1;
    }
}

// ---- k_attn: alpha@Wh, deferred normalization, local shift mx=lrelu(src).
// Block = (bh, 16-row n-tile). Wave w owns m-slab [w*256,(w+1)*256). ----
__global__ __launch_bounds__(256) void k_attn(const unsigned long long* __restrict__ pack,
                                              const float* __restrict__ srcv,
                                              const float* __restrict__ dstv,
                                              const unsigned short* __restrict__ WhT,
                                              float* __restrict__ hp) {
    __shared__ float red[4][16][68];     // first 1024 floats alias dsts[4][256]
    __shared__ float ssum[4][16];
    float* dsts = &red[0][0][0];

    int tid = threadIdx.x;
    int bt = blockIdx.x;
    int bh = bt >> 6;
    int n0 = (bt & 63) * 16;
    int b = bh >> 2;
    int w = tid >> 6, lane = tid & 63;
    int rowLane = lane & 15, quad = lane >> 4;
    int n = n0 + rowLane;

    // stage own wave's dst slab (wave-local; in-wave lgkmcnt ordering suffices)
    {
        float4 v = *(const float4*)(dstv + bh * N + w * 256 + lane * 4);
        *(float4*)(dsts + w * 256 + lane * 4) = v;
    }
    const uint4* pbp = (const uint4*)((const unsigned char*)(pack + ((size_t)(b * N + n)) * 16) + w * 32);
    uint4 pbv0 = pbp[0];
    uint4 pbv1 = pbp[1];
    float src = srcv[bh * N + n];
    float mx = src > 0.f ? src : 0.2f * src;   // local stable shift

    unsigned words[8] = {pbv0.x, pbv0.y, pbv0.z, pbv0.w, pbv1.x, pbv1.y, pbv1.z, pbv1.w};
    const unsigned short* wbase = WhT + ((size_t)bh * 32) * 2048 + rowLane * 32 + quad * 8;
    f32x4 acc[4] = {};
    float sum0 = 0.f, sum1 = 0.f;
#pragma unroll
    for (int t2 = 0; t2 < 8; ++t2) {
        unsigned bits = (words[t2] >> (quad * 8)) & 0xffu;
        float4 d0 = *(const float4*)(dsts + w * 256 + t2 * 32 + quad * 8);
        float4 d1 = *(const float4*)(dsts + w * 256 + t2 * 32 + quad * 8 + 4);
        float dd[8] = {d0.x, d0.y, d0.z, d0.w, d1.x, d1.y, d1.z, d1.w};
        unsigned pk[4];
#pragma unroll
        for (int j2 = 0; j2 < 4; ++j2) {
            float ea = src + dd[2 * j2];
            float eb = src + dd[2 * j2 + 1];
            ea = ea > 0.f ? ea : 0.2f * ea;
            eb = eb > 0.f ? eb : 0.2f * eb;
            float pa = ((bits >> (2 * j2)) & 1) ? __expf(ea - mx) : 0.f;
            float pb = ((bits >> (2 * j2 + 1)) & 1) ? __expf(eb - mx) : 0.f;
            sum0 += pa; sum1 += pb;
            // truncating bf16 pack (p >= 0; normalization absorbs <=0.4% bias)
            pk[j2] = (__float_as_uint(pb) & 0xffff0000u) | (__float_as_uint(pa) >> 16);
        }
        U8 u; u.u = make_uint4(pk[0], pk[1], pk[2], pk[3]);
        short8 af = u.s;
        const unsigned short* tb = wbase + (size_t)(w * 8 + t2) * 2048;
        acc[0] = __builtin_amdgcn_mfma_f32_16x16x32_bf16(af, *(const short8*)(tb + 0 * 512), acc[0], 0, 0, 0);
        acc[1] = __builtin_amdgcn_mfma_f32_16x16x32_bf16(af, *(const short8*)(tb + 1 * 512), acc[1], 0, 0, 0);
        acc[2] = __builtin_amdgcn_mfma_f32_16x16x32_bf16(af, *(const short8*)(tb + 2 * 512), acc[2], 0, 0, 0);
        acc[3] = __builtin_amdgcn_mfma_f32_16x16x32_bf16(af, *(const short8*)(tb + 3 * 512), acc[3], 0, 0, 0);
    }
    float sum = sum0 + sum1;
    sum += __shfl_xor(sum, 16, 64);
    sum += __shfl_xor(sum, 32, 64);
    if (quad == 0) ssum[w][rowLane] = sum;
    __syncthreads();  // ssum visible; dsts reads done -> red may overwrite
#pragma unroll
    for (int c = 0; c < 4; ++c)
#pragma unroll
        for (int r = 0; r < 4; ++r)
            red[w][quad * 4 + r][c * 16 + rowLane] = acc[c][r];
    __syncthreads();
    int row = tid >> 4, col4 = (tid & 15) * 4;
    float4 s = make_float4(0.f, 0.f, 0.f, 0.f);
#pragma unroll
    for (int ww = 0; ww < 4; ++ww) {
        float4 v = *(const float4*)&red[ww][row][col4];
        s.x += v.x; s.y += v.y; s.z += v.z; s.w += v.w;
    }
    float invr = 1.0f / (ssum[0][row] + ssum[1][row] + ssum[2][row] + ssum[3][row]);
    s.x *= invr; s.y *= invr; s.z *= invr; s.w *= invr;
    *(float4*)&hp[((size_t)bh * N + n0 + row) * DH + col4] = s;
}

// ---- k_ln: LN(h + concat(hp)); emits swizzled bf16 for next layer ----
__global__ __launch_bounds__(256) void k_ln(const float* __restrict__ h,
                                            const float* __restrict__ hp,
                                            const float* __restrict__ scale,
                                            const float* __restrict__ bias,
                                            float* __restrict__ out,
                                            unsigned short* __restrict__ h_sw,
                                            int layer, int has_next) {
    __shared__ float red[8];
    int bn = blockIdx.x;
    int b = bn >> 10, n = bn & 1023;
    int c = threadIdx.x;
    int hh = c >> 6, k = c & 63;
    float x = h[(size_t)bn * D + c] + hp[((size_t)(b * H + hh) * N + n) * DH + k];
    float s = x, s2 = x * x;
#pragma unroll
    for (int off = 32; off; off >>= 1) {
        s += __shfl_xor(s, off, 64);
        s2 += __shfl_xor(s2, off, 64);
    }
    int w = c >> 6, lane = c & 63;
    if (lane == 0) { red[w] = s; red[4 + w] = s2; }
    __syncthreads();
    s = red[0] + red[1] + red[2] + red[3];
    s2 = red[4] + red[5] + red[6] + red[7];
    float mu = s * (1.0f / D);
    float var = s2 * (1.0f / D) - mu * mu;
    float r = rsqrtf(var + 1e-5f);
    float y = (x - mu) * r * scale[layer * D + c] + bias[layer * D + c];
    out[(size_t)bn * D + c] = y;
    if (has_next)
        h_sw[(((size_t)b * 64 + (n >> 4)) * 8 + (c >> 5)) * 512 + (n & 15) * 32 + (c & 31)] = f2bf(y);
}

extern "C" void kernel_launch(void* const* d_in, const int* in_sizes, int n_in,
                              void* d_out, int out_size, void* d_ws, size_t ws_size,
                              hipStream_t stream) {
    const int* cfg_adj = (const int*)d_in[0];
    const int* cfg_nodes = (const int*)d_in[1];
    const int* cfg_len = (const int*)d_in[2];
    const float* emb = (const float*)d_in[3];
    const float* W = (const float*)d_in[4];
    const float* a_src = (const float*)d_in[5];
    const float* a_dst = (const float*)d_in[6];
    const float* ln_scale = (const float*)d_in[7];
    const float* ln_bias = (const float*)d_in[8];
    float* out = (float*)d_out;
    float* ws = (float*)d_ws;

    float* h = ws;
    float* hp = h + (size_t)B * N * D;
    float* srcv = hp + (size_t)B * H * N * DH;
    float* dstv = srcv + (size_t)B * H * N;
    unsigned short* h_sw = (unsigned short*)(dstv + (size_t)B * H * N);
    unsigned short* WhT = h_sw + (size_t)B * N * D;
    unsigned short* WT_sw = WhT + (size_t)B * H * DH * N;
    unsigned short* emb_bf = WT_sw + (size_t)NLAYERS * H * DH * D;
    unsigned long long* pack = (unsigned long long*)(emb_bf + (size_t)V * D);

    k_pre1<<<PRE1_GRID, 256, 0, stream>>>(cfg_adj, W, cfg_len, emb, pack, WT_sw,
                                          emb_bf, out + (size_t)B * N * D);
    k_nodefeat<<<B * N / 8, 256, 0, stream>>>(cfg_nodes, emb_bf, h, h_sw);
    for (int l = 0; l < NLAYERS; ++l) {
        k_wh<<<dim3(B * 64, H), 256, 0, stream>>>(
            h_sw, WT_sw + (size_t)l * H * 8 * 2048,
            a_src + (size_t)l * H * DH, a_dst + (size_t)l * H * DH,
            WhT, srcv, dstv);
        k_attn<<<B * H * 64, 256, 0, stream>>>(pack, srcv, dstv, WhT, hp);
        k_ln<<<B * N, 256, 0, stream>>>(h, hp, ln_scale, ln_bias,
                                        (l == NLAYERS - 1) ? out : h, h_sw,
                                        l, l < NLAYERS - 1 ? 1 : 0);
    }
}